// Round 6
// baseline (203.090 us; speedup 1.0000x reference)
//
#include <hip/hip_runtime.h>
#include <cmath>

#define ROWS      16384
#define SEQLEN    8192
#define BATCH     2
#define NHEADS    24
#define HEADDIM   16
#define D_STATE   16
#define D_INNER   384
#define D_MODEL   192
#define D_IN_PROJ 808
#define CONV_DIM  400
#define NCHUNKS   32
#define CHUNK     256
#define EPS       1e-5f

typedef short bf16x8 __attribute__((ext_vector_type(8)));
typedef float f32x4  __attribute__((ext_vector_type(4)));
typedef unsigned short us4v __attribute__((ext_vector_type(4)));
typedef unsigned short us8v __attribute__((ext_vector_type(8)));

__device__ __forceinline__ float silu_f(float x) { return x / (1.0f + expf(-x)); }
__device__ __forceinline__ float softplus_f(float x) { return (x > 20.0f) ? x : log1pf(expf(x)); }
__device__ __forceinline__ unsigned short f2bf(float x) {
  unsigned u = __builtin_bit_cast(unsigned, x);
  u += 0x7fff + ((u >> 16) & 1);
  return (unsigned short)(u >> 16);
}
__device__ __forceinline__ float bf2f(unsigned short s) {
  unsigned u = (unsigned)s << 16;
  return __builtin_bit_cast(float, u);
}

// ---------------------------------------------------------------------------
// K0: fp32 -> bf16 conversion for u, W_in, W_out
// ---------------------------------------------------------------------------
__global__ __launch_bounds__(256)
void cvt3_kernel(const float* __restrict__ a, unsigned short* __restrict__ ao, long na,
                 const float* __restrict__ b, unsigned short* __restrict__ bo, long nb,
                 const float* __restrict__ c, unsigned short* __restrict__ co, long nc) {
  const long t0 = na >> 2, t1 = t0 + (nb >> 2), t2 = t1 + (nc >> 2);
  const long stride = (long)gridDim.x * blockDim.x;
  for (long i = (long)blockIdx.x * blockDim.x + threadIdx.x; i < t2; i += stride) {
    const float4* s; us4v* d; long j;
    if (i < t0)      { s = (const float4*)a; d = (us4v*)ao; j = i; }
    else if (i < t1) { s = (const float4*)b; d = (us4v*)bo; j = i - t0; }
    else             { s = (const float4*)c; d = (us4v*)co; j = i - t1; }
    float4 v = s[j];
    us4v o = { f2bf(v.x), f2bf(v.y), f2bf(v.z), f2bf(v.w) };
    d[j] = o;
  }
}

// ---------------------------------------------------------------------------
// MFMA bf16 GEMM: C[M,N] = A[M,K] * W[N,K]^T, double-buffered LDS
// ---------------------------------------------------------------------------
template<bool OUT_BF16>
__launch_bounds__(256, 3)
__global__ void gemm_bf16(const unsigned short* __restrict__ A,
                          const unsigned short* __restrict__ W,
                          void* __restrict__ Cp, int M, int N, int K) {
  constexpr int BM = 128, BN = 128, BK = 32, LDK = 40;
  __shared__ unsigned short As[2][BM * LDK];
  __shared__ unsigned short Ws[2][BN * LDK];
  const int tid  = threadIdx.x;
  const int wid  = tid >> 6, lane = tid & 63;
  const int wr   = wid >> 1, wc = wid & 1;
  const int fr   = lane & 15, fq = lane >> 4;
  const long m0  = (long)blockIdx.y * BM;
  const int  n0  = blockIdx.x * BN;

  f32x4 acc[4][4] = {};

  auto stage = [&](int k0, int buf) {
#pragma unroll
    for (int p = 0; p < 2; ++p) {
      int flat = p * 2048 + tid * 8;
      int r = flat >> 5, c = flat & 31;
      us8v v = *(const us8v*)(A + (m0 + r) * (long)K + k0 + c);
      *(us8v*)&As[buf][r * LDK + c] = v;
    }
#pragma unroll
    for (int p = 0; p < 2; ++p) {
      int flat = p * 2048 + tid * 8;
      int r = flat >> 5, c = flat & 31;
      int gn = n0 + r;
      us8v v = { 0, 0, 0, 0, 0, 0, 0, 0 };
      if (gn < N) v = *(const us8v*)(W + (long)gn * K + k0 + c);
      *(us8v*)&Ws[buf][r * LDK + c] = v;
    }
  };

  const int nk = K / BK;
  stage(0, 0);
  __syncthreads();
  for (int kt = 0; kt < nk; ++kt) {
    const int cur = kt & 1;
    if (kt + 1 < nk) stage((kt + 1) * BK, cur ^ 1);
    bf16x8 af[4], bfr[4];
#pragma unroll
    for (int m = 0; m < 4; ++m)
      af[m] = *(const bf16x8*)&As[cur][(wr * 64 + m * 16 + fr) * LDK + fq * 8];
#pragma unroll
    for (int n = 0; n < 4; ++n)
      bfr[n] = *(const bf16x8*)&Ws[cur][(wc * 64 + n * 16 + fr) * LDK + fq * 8];
#pragma unroll
    for (int m = 0; m < 4; ++m)
#pragma unroll
      for (int n = 0; n < 4; ++n)
        acc[m][n] = __builtin_amdgcn_mfma_f32_16x16x32_bf16(af[m], bfr[n], acc[m][n], 0, 0, 0);
    __syncthreads();
  }

#pragma unroll
  for (int m = 0; m < 4; ++m)
#pragma unroll
    for (int n = 0; n < 4; ++n)
#pragma unroll
      for (int j = 0; j < 4; ++j) {
        long gm = m0 + wr * 64 + m * 16 + fq * 4 + j;
        int  gn = n0 + wc * 64 + n * 16 + fr;
        if (gn < N) {
          if (OUT_BF16) ((unsigned short*)Cp)[gm * N + gn] = f2bf(acc[m][n][j]);
          else          ((float*)Cp)[gm * N + gn] = acc[m][n][j];
        }
      }
}

// ---------------------------------------------------------------------------
// fp32 SIMT GEMM (tiny K1b only: N=16)
// ---------------------------------------------------------------------------
template<int BM, int BN, int BK, int TM, int TN>
__launch_bounds__((BM / TM) * (BN / TN))
__global__ void gemm_nt(const float* __restrict__ A, const float* __restrict__ W,
                        float* __restrict__ C, int M, int N, int K) {
  __shared__ float As[BK][BM + 4];
  __shared__ float Ws[BK][BN + 4];
  constexpr int NTX = BN / TN;
  constexpr int NT  = (BM / TM) * (BN / TN);
  const int tid = threadIdx.x;
  const int tx  = tid % NTX;
  const int ty  = tid / NTX;
  const long m0 = (long)blockIdx.y * BM;
  const long n0 = (long)blockIdx.x * BN;
  float acc[TM][TN] = {};

  for (int k0 = 0; k0 < K; k0 += BK) {
    for (int i = tid; i < BM * BK; i += NT) {
      int m = i / BK, kk = i % BK;
      long gm = m0 + m;
      As[kk][m] = (gm < M) ? A[gm * K + (k0 + kk)] : 0.0f;
    }
    for (int i = tid; i < BN * BK; i += NT) {
      int n = i / BK, kk = i % BK;
      long gn = n0 + n;
      Ws[kk][n] = (gn < N) ? W[gn * K + (k0 + kk)] : 0.0f;
    }
    __syncthreads();
#pragma unroll
    for (int kk = 0; kk < BK; ++kk) {
      float a[TM], w[TN];
#pragma unroll
      for (int i = 0; i < TM; ++i) a[i] = As[kk][ty * TM + i];
#pragma unroll
      for (int j = 0; j < TN; ++j) w[j] = Ws[kk][tx * TN + j];
#pragma unroll
      for (int i = 0; i < TM; ++i)
#pragma unroll
        for (int j = 0; j < TN; ++j)
          acc[i][j] += a[i] * w[j];
    }
    __syncthreads();
  }
#pragma unroll
  for (int i = 0; i < TM; ++i) {
    long gm = m0 + ty * TM + i;
    if (gm >= M) continue;
#pragma unroll
    for (int j = 0; j < TN; ++j) {
      long gn = n0 + tx * TN + j;
      if (gn < N) C[gm * N + gn] = acc[i][j];
    }
  }
}

// ---------------------------------------------------------------------------
// K2: vectorized depthwise causal conv + silu + dt softplus.
// One thread per (8-time-block, role). Roles: 48 x-groups(8ch), 2 B, 2 C, 24 dt.
// All conv loads/stores are 16B vectors; outputs head-major.
// ---------------------------------------------------------------------------
#define NTB   (ROWS / 8)
#define ROLES 76

__global__ __launch_bounds__(256)
void conv_dt_vec(const unsigned short* __restrict__ zxbdt, const float* __restrict__ cproj,
                 const float* __restrict__ conv_w, const float* __restrict__ conv_b,
                 const float* __restrict__ conv_w_b, const float* __restrict__ conv_b_b,
                 const float* __restrict__ dt_bias,
                 unsigned short* __restrict__ xoT, unsigned short* __restrict__ Bo,
                 unsigned short* __restrict__ Co, float* __restrict__ dtoT) {
  const int idx = blockIdx.x * 256 + threadIdx.x;
  if (idx >= NTB * ROLES) return;
  const int tb = idx / ROLES;
  const int rl = idx % ROLES;
  const int b  = tb / (SEQLEN / 8);
  const int t0 = (tb % (SEQLEN / 8)) * 8;
  const size_t rowbase = (size_t)b * SEQLEN;

  if (rl < 48) {
    // ---- x channels: 8 channels starting at c0 = rl*8 ----
    const int c0 = rl * 8;
    const int h = rl >> 1, i0 = (rl & 1) * 8;
    float w[8][4], bias[8];
#pragma unroll
    for (int ch = 0; ch < 8; ++ch) {
      const float4 wv = *(const float4*)(conv_w + (c0 + ch) * 4);
      w[ch][0] = wv.x; w[ch][1] = wv.y; w[ch][2] = wv.z; w[ch][3] = wv.w;
      bias[ch] = conv_b[c0 + ch];
    }
    float xr[11][8];
#pragma unroll
    for (int r = 0; r < 11; ++r) {
      const int t = t0 + r - 3;
      if (t >= 0) {
        us8v v = *(const us8v*)(zxbdt + (rowbase + t) * D_IN_PROJ + D_INNER + c0);
#pragma unroll
        for (int ch = 0; ch < 8; ++ch) xr[r][ch] = bf2f(v[ch]);
      } else {
#pragma unroll
        for (int ch = 0; ch < 8; ++ch) xr[r][ch] = 0.f;
      }
    }
#pragma unroll
    for (int tt = 0; tt < 8; ++tt) {
      us8v o;
#pragma unroll
      for (int ch = 0; ch < 8; ++ch) {
        float acc = bias[ch] + w[ch][0] * xr[tt][ch] + w[ch][1] * xr[tt + 1][ch]
                  + w[ch][2] * xr[tt + 2][ch] + w[ch][3] * xr[tt + 3][ch];
        o[ch] = f2bf(silu_f(acc));
      }
      *(us8v*)(xoT + ((size_t)(b * NHEADS + h) * SEQLEN + t0 + tt) * HEADDIM + i0) = o;
    }
  } else if (rl < 50) {
    // ---- B channels: 8 channels at c0 = (rl-48)*8 of 16 ----
    const int c0 = (rl - 48) * 8;
    float w[8][4], bias[8];
#pragma unroll
    for (int ch = 0; ch < 8; ++ch) {
      const float4 wv = *(const float4*)(conv_w + (D_INNER + c0 + ch) * 4);
      w[ch][0] = wv.x; w[ch][1] = wv.y; w[ch][2] = wv.z; w[ch][3] = wv.w;
      bias[ch] = conv_b[D_INNER + c0 + ch];
    }
    float xr[11][8];
#pragma unroll
    for (int r = 0; r < 11; ++r) {
      const int t = t0 + r - 3;
      if (t >= 0) {
        us8v v = *(const us8v*)(zxbdt + (rowbase + t) * D_IN_PROJ + D_INNER + CONV_DIM - D_STATE + c0);
#pragma unroll
        for (int ch = 0; ch < 8; ++ch) xr[r][ch] = bf2f(v[ch]);
      } else {
#pragma unroll
        for (int ch = 0; ch < 8; ++ch) xr[r][ch] = 0.f;
      }
    }
#pragma unroll
    for (int tt = 0; tt < 8; ++tt) {
      us8v o;
#pragma unroll
      for (int ch = 0; ch < 8; ++ch) {
        float acc = bias[ch] + w[ch][0] * xr[tt][ch] + w[ch][1] * xr[tt + 1][ch]
                  + w[ch][2] * xr[tt + 2][ch] + w[ch][3] * xr[tt + 3][ch];
        o[ch] = f2bf(silu_f(acc));
      }
      *(us8v*)(Bo + (rowbase + t0 + tt) * D_STATE + c0) = o;
    }
  } else if (rl < 52) {
    // ---- C channels (from fp32 cproj): 8 at c0 = (rl-50)*8 ----
    const int c0 = (rl - 50) * 8;
    float w[8][4], bias[8];
#pragma unroll
    for (int ch = 0; ch < 8; ++ch) {
      const float4 wv = *(const float4*)(conv_w_b + (c0 + ch) * 4);
      w[ch][0] = wv.x; w[ch][1] = wv.y; w[ch][2] = wv.z; w[ch][3] = wv.w;
      bias[ch] = conv_b_b[c0 + ch];
    }
    float xr[11][8];
#pragma unroll
    for (int r = 0; r < 11; ++r) {
      const int t = t0 + r - 3;
      if (t >= 0) {
        const float4* p = (const float4*)(cproj + (rowbase + t) * D_STATE + c0);
        float4 v0 = p[0], v1 = p[1];
        xr[r][0] = v0.x; xr[r][1] = v0.y; xr[r][2] = v0.z; xr[r][3] = v0.w;
        xr[r][4] = v1.x; xr[r][5] = v1.y; xr[r][6] = v1.z; xr[r][7] = v1.w;
      } else {
#pragma unroll
        for (int ch = 0; ch < 8; ++ch) xr[r][ch] = 0.f;
      }
    }
#pragma unroll
    for (int tt = 0; tt < 8; ++tt) {
      us8v o;
#pragma unroll
      for (int ch = 0; ch < 8; ++ch) {
        float acc = bias[ch] + w[ch][0] * xr[tt][ch] + w[ch][1] * xr[tt + 1][ch]
                  + w[ch][2] * xr[tt + 2][ch] + w[ch][3] * xr[tt + 3][ch];
        o[ch] = f2bf(silu_f(acc));
      }
      *(us8v*)(Co + (rowbase + t0 + tt) * D_STATE + c0) = o;
    }
  } else {
    // ---- dt: head h = rl-52 ----
    const int h = rl - 52;
    const float bias = dt_bias[h];
#pragma unroll
    for (int tt = 0; tt < 8; ++tt) {
      float v = bf2f(zxbdt[(rowbase + t0 + tt) * D_IN_PROJ + (D_IN_PROJ - NHEADS) + h]) + bias;
      dtoT[(size_t)(b * NHEADS + h) * SEQLEN + t0 + tt] = softplus_f(v);
    }
  }
}

// ---------------------------------------------------------------------------
// K3 (MFMA): per (h, chunk, b) block, 4 waves. Head-major in/out.
// ---------------------------------------------------------------------------
__global__ __launch_bounds__(256, 2)
void ssd_mfma_kernel(const unsigned short* __restrict__ xoT, const unsigned short* __restrict__ Bo,
                     const unsigned short* __restrict__ Co, const float* __restrict__ dtoT,
                     const float* __restrict__ A_log,
                     unsigned short* __restrict__ YdT, float* __restrict__ acum_g,
                     float* __restrict__ csum_g, float* __restrict__ stloc) {
  const int h    = blockIdx.x;
  const int cidx = blockIdx.y;
  const int b    = blockIdx.z;
  const int l    = threadIdx.x;
  const int t    = cidx * CHUNK + l;
  const size_t row  = (size_t)b * SEQLEN + t;
  const size_t hrow = (size_t)(b * NHEADS + h) * SEQLEN + t;
  const int wid = l >> 6, lane = l & 63;
  const int fr  = lane & 15, g = lane >> 4;

  __shared__ unsigned short Bs[256 * 24 + 32];
  __shared__ unsigned short Cs[256 * 40];
  __shared__ unsigned short xsT[16 * 264];
  __shared__ unsigned short BwT[16 * 264];
  __shared__ unsigned short Ps[4][16 * 40];
  __shared__ float sc[CHUNK];
  __shared__ float sred[4 * 256];
  __shared__ float wsum[4];

  const float Ah  = -expf(A_log[h]);
  const float dtv = dtoT[hrow];

  float v = dtv * Ah;
#pragma unroll
  for (int off = 1; off < 64; off <<= 1) {
    float u = __shfl_up(v, off, 64);
    if (lane >= off) v += u;
  }
  if (lane == 63) wsum[wid] = v;

  us8v b0, b1;
  {
    const us8v z8 = { 0, 0, 0, 0, 0, 0, 0, 0 };
    const us8v* bp = (const us8v*)(Bo + row * D_STATE);
    b0 = bp[0]; b1 = bp[1];
    *(us8v*)&Bs[l * 24 + 0] = b0;
    *(us8v*)&Bs[l * 24 + 8] = b1;
    *(us8v*)&Bs[l * 24 + 16] = z8;
    if (l < 32) Bs[256 * 24 + l] = 0;
    const us8v* cp = (const us8v*)(Co + row * D_STATE);
    *(us8v*)&Cs[l * 40 + 0]  = cp[0];
    *(us8v*)&Cs[l * 40 + 8]  = cp[1];
    *(us8v*)&Cs[l * 40 + 16] = z8;
    *(us8v*)&Cs[l * 40 + 24] = z8;
    const us8v* xp = (const us8v*)(xoT + hrow * HEADDIM);
    us8v x0 = xp[0], x1 = xp[1];
#pragma unroll
    for (int q = 0; q < 8; ++q) {
      xsT[q * 264 + l]       = f2bf(bf2f(x0[q]) * dtv);
      xsT[(q + 8) * 264 + l] = f2bf(bf2f(x1[q]) * dtv);
    }
  }
  __syncthreads();   // #1

  float pre = 0.f, ctot = 0.f;
#pragma unroll
  for (int w = 0; w < 4; ++w) {
    float s = wsum[w];
    if (w < wid) pre += s;
    ctot += s;
  }
  v += pre;
  sc[l] = v;
  acum_g[hrow] = v;
  if (l == CHUNK - 1) csum_g[(b * NHEADS + h) * NCHUNKS + cidx] = v;
  const float wdv = __expf(ctot - v);
#pragma unroll
  for (int q = 0; q < 8; ++q) {
    BwT[q * 264 + l]       = f2bf(bf2f(b0[q]) * wdv);
    BwT[(q + 8) * 264 + l] = f2bf(bf2f(b1[q]) * wdv);
  }
  __syncthreads();   // #2

  {
    f32x4 accS = {};
    const int s0 = wid * 64;
#pragma unroll
    for (int k2 = 0; k2 < 2; ++k2) {
      bf16x8 af = *(const bf16x8*)&BwT[fr * 264 + s0 + 32 * k2 + 8 * g];
      bf16x8 bb = *(const bf16x8*)&xsT[fr * 264 + s0 + 32 * k2 + 8 * g];
      accS = __builtin_amdgcn_mfma_f32_16x16x32_bf16(af, bb, accS, 0, 0, 0);
    }
    *(f32x4*)&sred[wid * 256 + fr * 16 + 4 * g] = accS;
  }

  const int strips[4] = { wid, 7 - wid, 8 + wid, 15 - wid };
  const f32x4 zf = { 0.f, 0.f, 0.f, 0.f };
#pragma unroll
  for (int q = 0; q < 4; ++q) {
    const int lt = strips[q];
    f32x4 acc = zf;
    const bf16x8 cf = *(const bf16x8*)&Cs[(lt * 16 + fr) * 40 + 8 * g];
    const float acl = sc[lt * 16 + fr];
    const int   lg  = lt * 16 + fr;
    const int npair = (lt + 2) >> 1;
    for (int sp = 0; sp < npair; ++sp) {
#pragma unroll
      for (int ti = 0; ti < 2; ++ti) {
        const int st = 2 * sp + ti;
        if (st <= lt) {
          bf16x8 bfg = *(const bf16x8*)&Bs[(st * 16 + fr) * 24 + 8 * g];
          f32x4 G = __builtin_amdgcn_mfma_f32_16x16x32_bf16(bfg, cf, zf, 0, 0, 0);
          f32x4 se = *(const f32x4*)&sc[st * 16 + 4 * g];
          uint2 pk;
          {
            const int sbase = st * 16 + 4 * g;
            float w0 = (sbase + 0 <= lg) ? __expf(acl - se[0]) : 0.f;
            float w1 = (sbase + 1 <= lg) ? __expf(acl - se[1]) : 0.f;
            float w2 = (sbase + 2 <= lg) ? __expf(acl - se[2]) : 0.f;
            float w3 = (sbase + 3 <= lg) ? __expf(acl - se[3]) : 0.f;
            pk.x = (unsigned)f2bf(G[0] * w0) | ((unsigned)f2bf(G[1] * w1) << 16);
            pk.y = (unsigned)f2bf(G[2] * w2) | ((unsigned)f2bf(G[3] * w3) << 16);
          }
          *(uint2*)&Ps[wid][fr * 40 + 16 * ti + 4 * g] = pk;
        } else {
          uint2 zz; zz.x = 0u; zz.y = 0u;
          *(uint2*)&Ps[wid][fr * 40 + 16 * ti + 4 * g] = zz;
        }
      }
      const bf16x8 pf = *(const bf16x8*)&Ps[wid][fr * 40 + 8 * g];
      const bf16x8 xf = *(const bf16x8*)&xsT[fr * 264 + sp * 32 + 8 * g];
      acc = __builtin_amdgcn_mfma_f32_16x16x32_bf16(xf, pf, acc, 0, 0, 0);
    }
    us4v o = { f2bf(acc[0]), f2bf(acc[1]), f2bf(acc[2]), f2bf(acc[3]) };
    *(us4v*)(YdT + ((size_t)(b * NHEADS + h) * SEQLEN + (size_t)cidx * CHUNK + lt * 16 + fr) * HEADDIM
             + 4 * g) = o;
  }

  __syncthreads();   // #3
  {
    float s = sred[l] + sred[256 + l] + sred[512 + l] + sred[768 + l];
    stloc[((size_t)(b * NCHUNKS + cidx) * NHEADS + h) * 256 + l] = s;
  }
}

// ---------------------------------------------------------------------------
// K4: sequential inter-chunk state recurrence ([p][n] layout)
// ---------------------------------------------------------------------------
__global__ __launch_bounds__(256)
void chunk_scan_kernel(const float* __restrict__ stloc, const float* __restrict__ csum_g,
                       float* __restrict__ stpre) {
  const int b  = blockIdx.x / NHEADS;
  const int h  = blockIdx.x % NHEADS;
  const int pn = threadIdx.x;
  float S = 0.0f;
  for (int c = 0; c < NCHUNKS; ++c) {
    const size_t idx = ((size_t)(b * NCHUNKS + c) * NHEADS + h) * 256 + pn;
    stpre[idx] = S;
    S = __expf(csum_g[(b * NHEADS + h) * NCHUNKS + c]) * S + stloc[idx];
  }
}

// ---------------------------------------------------------------------------
// K5: Y_off + D*x, silu(z) gate, RMSNorm -> row-major bf16 yn
// ---------------------------------------------------------------------------
__global__ __launch_bounds__(384)
void yoff_norm_kernel(const unsigned short* __restrict__ YdT, const unsigned short* __restrict__ xoT,
                      const unsigned short* __restrict__ Co, const float* __restrict__ acum_g,
                      const float* __restrict__ stpre, const float* __restrict__ Dvec,
                      const unsigned short* __restrict__ zxbdt, const float* __restrict__ norm_w,
                      unsigned short* __restrict__ yn) {
  const int row  = blockIdx.x;
  const int b    = row / SEQLEN, t = row % SEQLEN;
  const int cidx = t / CHUNK;
  const int d    = threadIdx.x;
  const int h    = d >> 4, p = d & 15;

  __shared__ float Cl[16];
  __shared__ float red[6];
  if (d < 16) Cl[d] = bf2f(Co[(size_t)row * D_STATE + d]);
  __syncthreads();

  const size_t hrow = (size_t)(b * NHEADS + h) * SEQLEN + t;
  const float* S = stpre + ((size_t)(b * NCHUNKS + cidx) * NHEADS + h) * 256 + p * 16;
  float dot = 0.0f;
#pragma unroll
  for (int n = 0; n < 16; ++n) dot += Cl[n] * S[n];
  const float acl = acum_g[hrow];
  float y = bf2f(YdT[hrow * HEADDIM + p]) + __expf(acl) * dot
          + Dvec[h] * bf2f(xoT[hrow * HEADDIM + p]);
  const float z = bf2f(zxbdt[(size_t)row * D_IN_PROJ + d]);
  const float yg = y * silu_f(z);

  float v = yg * yg;
#pragma unroll
  for (int off = 32; off > 0; off >>= 1) v += __shfl_down(v, off);
  if ((d & 63) == 0) red[d >> 6] = v;
  __syncthreads();
  const float tot = red[0] + red[1] + red[2] + red[3] + red[4] + red[5];
  const float scale = rsqrtf(tot * (1.0f / D_INNER) + EPS);
  yn[(size_t)row * D_INNER + d] = f2bf(yg * scale * norm_w[d]);
}

// ---------------------------------------------------------------------------
extern "C" void kernel_launch(void* const* d_in, const int* in_sizes, int n_in,
                              void* d_out, int out_size, void* d_ws, size_t ws_size,
                              hipStream_t stream) {
  const float* u        = (const float*)d_in[0];
  const float* support  = (const float*)d_in[1];
  const float* W_in     = (const float*)d_in[2];
  const float* W_in_b   = (const float*)d_in[3];
  const float* conv_w   = (const float*)d_in[4];
  const float* conv_b   = (const float*)d_in[5];
  const float* conv_w_b = (const float*)d_in[6];
  const float* conv_b_b = (const float*)d_in[7];
  const float* dt_bias  = (const float*)d_in[8];
  const float* A_log    = (const float*)d_in[9];
  const float* Dvec     = (const float*)d_in[10];
  const float* norm_w   = (const float*)d_in[11];
  const float* W_out    = (const float*)d_in[12];
  float* out = (float*)d_out;
  char* wsb  = (char*)d_ws;

  unsigned short* u_b   = (unsigned short*)(wsb);
  unsigned short* Wi_b  = u_b  + (size_t)ROWS * D_MODEL;
  unsigned short* Wo_b  = Wi_b + (size_t)D_IN_PROJ * D_MODEL;
  unsigned short* zxbdt = Wo_b + (size_t)D_MODEL * D_INNER;
  unsigned short* xoT   = zxbdt + (size_t)ROWS * D_IN_PROJ;      // [b][h][t][16]
  unsigned short* Bo    = xoT + (size_t)ROWS * D_INNER;          // [b][t][16]
  unsigned short* Co    = Bo + (size_t)ROWS * D_STATE;           // [b][t][16]
  unsigned short* YdT   = Co + (size_t)ROWS * D_STATE;           // [b][h][t][16]
  unsigned short* yn    = YdT + (size_t)ROWS * D_INNER;          // [row][384]
  float* cproj = (float*)(yn + (size_t)ROWS * D_INNER);
  float* dtoT  = cproj + (size_t)ROWS * D_STATE;                 // [b][h][t]
  float* acum  = dtoT  + (size_t)ROWS * NHEADS;                  // [b][h][t]
  float* csum  = acum  + (size_t)BATCH * NHEADS * SEQLEN;
  float* stloc = csum  + (size_t)BATCH * NHEADS * NCHUNKS;
  float* stpre = stloc + (size_t)BATCH * NCHUNKS * NHEADS * 256;

  cvt3_kernel<<<2048, 256, 0, stream>>>(u, u_b, (long)ROWS * D_MODEL,
                                        W_in, Wi_b, (long)D_IN_PROJ * D_MODEL,
                                        W_out, Wo_b, (long)D_MODEL * D_INNER);
  gemm_bf16<true><<<dim3((D_IN_PROJ + 127) / 128, ROWS / 128), 256, 0, stream>>>(
      u_b, Wi_b, zxbdt, ROWS, D_IN_PROJ, D_MODEL);
  gemm_nt<64, 16, 16, 4, 1><<<dim3(1, ROWS / 64), 256, 0, stream>>>(
      support, W_in_b, cproj, ROWS, D_STATE, D_MODEL);
  conv_dt_vec<<<(NTB * ROLES + 255) / 256, 256, 0, stream>>>(
      zxbdt, cproj, conv_w, conv_b, conv_w_b, conv_b_b, dt_bias, xoT, Bo, Co, dtoT);
  ssd_mfma_kernel<<<dim3(NHEADS, NCHUNKS, BATCH), 256, 0, stream>>>(
      xoT, Bo, Co, dtoT, A_log, YdT, acum, csum, stloc);
  chunk_scan_kernel<<<BATCH * NHEADS, 256, 0, stream>>>(stloc, csum, stpre);
  yoff_norm_kernel<<<ROWS, 384, 0, stream>>>(YdT, xoT, Co, acum, stpre, Dvec, zxbdt,
                                             norm_w, yn);
  gemm_bf16<false><<<dim3((D_MODEL + 127) / 128, ROWS / 128), 256, 0, stream>>>(
      yn, Wo_b, out, ROWS, D_MODEL, D_INNER);
}

// Round 7
// 181.464 us; speedup vs baseline: 1.1192x; 1.1192x over previous
//
#include <hip/hip_runtime.h>
#include <cmath>

#define ROWS      16384
#define SEQLEN    8192
#define BATCH     2
#define NHEADS    24
#define HEADDIM   16
#define D_STATE   16
#define D_INNER   384
#define D_MODEL   192
#define D_IN_PROJ 808
#define CONV_DIM  400
#define NCHUNKS   32
#define CHUNK     256
#define EPS       1e-5f

typedef short bf16x8 __attribute__((ext_vector_type(8)));
typedef float f32x4  __attribute__((ext_vector_type(4)));
typedef unsigned short us4v __attribute__((ext_vector_type(4)));
typedef unsigned short us8v __attribute__((ext_vector_type(8)));

__device__ __forceinline__ float silu_f(float x) { return x / (1.0f + expf(-x)); }
__device__ __forceinline__ float softplus_f(float x) { return (x > 20.0f) ? x : log1pf(expf(x)); }
__device__ __forceinline__ unsigned short f2bf(float x) {
  unsigned u = __builtin_bit_cast(unsigned, x);
  u += 0x7fff + ((u >> 16) & 1);
  return (unsigned short)(u >> 16);
}
__device__ __forceinline__ float bf2f(unsigned short s) {
  unsigned u = (unsigned)s << 16;
  return __builtin_bit_cast(float, u);
}

// ---------------------------------------------------------------------------
// K0: fp32 -> bf16 conversion for u, W_in, W_out
// ---------------------------------------------------------------------------
__global__ __launch_bounds__(256)
void cvt3_kernel(const float* __restrict__ a, unsigned short* __restrict__ ao, long na,
                 const float* __restrict__ b, unsigned short* __restrict__ bo, long nb,
                 const float* __restrict__ c, unsigned short* __restrict__ co, long nc) {
  const long t0 = na >> 2, t1 = t0 + (nb >> 2), t2 = t1 + (nc >> 2);
  const long stride = (long)gridDim.x * blockDim.x;
  for (long i = (long)blockIdx.x * blockDim.x + threadIdx.x; i < t2; i += stride) {
    const float4* s; us4v* d; long j;
    if (i < t0)      { s = (const float4*)a; d = (us4v*)ao; j = i; }
    else if (i < t1) { s = (const float4*)b; d = (us4v*)bo; j = i - t0; }
    else             { s = (const float4*)c; d = (us4v*)co; j = i - t1; }
    float4 v = s[j];
    us4v o = { f2bf(v.x), f2bf(v.y), f2bf(v.z), f2bf(v.w) };
    d[j] = o;
  }
}

// ---------------------------------------------------------------------------
// MFMA bf16 GEMM: C[M,N] = A[M,K] * W[N,K]^T, double-buffered LDS
// ---------------------------------------------------------------------------
template<bool OUT_BF16>
__launch_bounds__(256, 3)
__global__ void gemm_bf16(const unsigned short* __restrict__ A,
                          const unsigned short* __restrict__ W,
                          void* __restrict__ Cp, int M, int N, int K) {
  constexpr int BM = 128, BN = 128, BK = 32, LDK = 40;
  __shared__ unsigned short As[2][BM * LDK];
  __shared__ unsigned short Ws[2][BN * LDK];
  const int tid  = threadIdx.x;
  const int wid  = tid >> 6, lane = tid & 63;
  const int wr   = wid >> 1, wc = wid & 1;
  const int fr   = lane & 15, fq = lane >> 4;
  const long m0  = (long)blockIdx.y * BM;
  const int  n0  = blockIdx.x * BN;

  f32x4 acc[4][4] = {};

  auto stage = [&](int k0, int buf) {
#pragma unroll
    for (int p = 0; p < 2; ++p) {
      int flat = p * 2048 + tid * 8;
      int r = flat >> 5, c = flat & 31;
      us8v v = *(const us8v*)(A + (m0 + r) * (long)K + k0 + c);
      *(us8v*)&As[buf][r * LDK + c] = v;
    }
#pragma unroll
    for (int p = 0; p < 2; ++p) {
      int flat = p * 2048 + tid * 8;
      int r = flat >> 5, c = flat & 31;
      int gn = n0 + r;
      us8v v = { 0, 0, 0, 0, 0, 0, 0, 0 };
      if (gn < N) v = *(const us8v*)(W + (long)gn * K + k0 + c);
      *(us8v*)&Ws[buf][r * LDK + c] = v;
    }
  };

  const int nk = K / BK;
  stage(0, 0);
  __syncthreads();
  for (int kt = 0; kt < nk; ++kt) {
    const int cur = kt & 1;
    if (kt + 1 < nk) stage((kt + 1) * BK, cur ^ 1);
    bf16x8 af[4], bfr[4];
#pragma unroll
    for (int m = 0; m < 4; ++m)
      af[m] = *(const bf16x8*)&As[cur][(wr * 64 + m * 16 + fr) * LDK + fq * 8];
#pragma unroll
    for (int n = 0; n < 4; ++n)
      bfr[n] = *(const bf16x8*)&Ws[cur][(wc * 64 + n * 16 + fr) * LDK + fq * 8];
#pragma unroll
    for (int m = 0; m < 4; ++m)
#pragma unroll
      for (int n = 0; n < 4; ++n)
        acc[m][n] = __builtin_amdgcn_mfma_f32_16x16x32_bf16(af[m], bfr[n], acc[m][n], 0, 0, 0);
    __syncthreads();
  }

#pragma unroll
  for (int m = 0; m < 4; ++m)
#pragma unroll
    for (int n = 0; n < 4; ++n)
#pragma unroll
      for (int j = 0; j < 4; ++j) {
        long gm = m0 + wr * 64 + m * 16 + fq * 4 + j;
        int  gn = n0 + wc * 64 + n * 16 + fr;
        if (gn < N) {
          if (OUT_BF16) ((unsigned short*)Cp)[gm * N + gn] = f2bf(acc[m][n][j]);
          else          ((float*)Cp)[gm * N + gn] = acc[m][n][j];
        }
      }
}

// ---------------------------------------------------------------------------
// fp32 SIMT GEMM (tiny K1b only: N=16)
// ---------------------------------------------------------------------------
template<int BM, int BN, int BK, int TM, int TN>
__launch_bounds__((BM / TM) * (BN / TN))
__global__ void gemm_nt(const float* __restrict__ A, const float* __restrict__ W,
                        float* __restrict__ C, int M, int N, int K) {
  __shared__ float As[BK][BM + 4];
  __shared__ float Ws[BK][BN + 4];
  constexpr int NTX = BN / TN;
  constexpr int NT  = (BM / TM) * (BN / TN);
  const int tid = threadIdx.x;
  const int tx  = tid % NTX;
  const int ty  = tid / NTX;
  const long m0 = (long)blockIdx.y * BM;
  const long n0 = (long)blockIdx.x * BN;
  float acc[TM][TN] = {};

  for (int k0 = 0; k0 < K; k0 += BK) {
    for (int i = tid; i < BM * BK; i += NT) {
      int m = i / BK, kk = i % BK;
      long gm = m0 + m;
      As[kk][m] = (gm < M) ? A[gm * K + (k0 + kk)] : 0.0f;
    }
    for (int i = tid; i < BN * BK; i += NT) {
      int n = i / BK, kk = i % BK;
      long gn = n0 + n;
      Ws[kk][n] = (gn < N) ? W[gn * K + (k0 + kk)] : 0.0f;
    }
    __syncthreads();
#pragma unroll
    for (int kk = 0; kk < BK; ++kk) {
      float a[TM], w[TN];
#pragma unroll
      for (int i = 0; i < TM; ++i) a[i] = As[kk][ty * TM + i];
#pragma unroll
      for (int j = 0; j < TN; ++j) w[j] = Ws[kk][tx * TN + j];
#pragma unroll
      for (int i = 0; i < TM; ++i)
#pragma unroll
        for (int j = 0; j < TN; ++j)
          acc[i][j] += a[i] * w[j];
    }
    __syncthreads();
  }
#pragma unroll
  for (int i = 0; i < TM; ++i) {
    long gm = m0 + ty * TM + i;
    if (gm >= M) continue;
#pragma unroll
    for (int j = 0; j < TN; ++j) {
      long gn = n0 + tx * TN + j;
      if (gn < N) C[gm * N + gn] = acc[i][j];
    }
  }
}

// ---------------------------------------------------------------------------
// K2: vectorized depthwise causal conv + silu + dt softplus.
// Role-pure block segments; bf16-packed register window (no spill).
//   blocks [0,384):    x channels   (tb = idx/48, rl = idx%48, 8ch x 8t each)
//   blocks [384,416):  B + C        (tb = idx/4,  q  = idx%4)
//   blocks [416,608):  dt           (tb = idx/24, h  = idx%24)
// ---------------------------------------------------------------------------
#define NTB      (ROWS / 8)
#define NBLK_X   (NTB * 48 / 256)
#define NBLK_BC  (NTB * 4 / 256)
#define NBLK_DT  (NTB * 24 / 256)

__global__ __launch_bounds__(256)
void conv_dt_vec(const unsigned short* __restrict__ zxbdt, const float* __restrict__ cproj,
                 const float* __restrict__ conv_w, const float* __restrict__ conv_b,
                 const float* __restrict__ conv_w_b, const float* __restrict__ conv_b_b,
                 const float* __restrict__ dt_bias,
                 unsigned short* __restrict__ xoT, unsigned short* __restrict__ Bo,
                 unsigned short* __restrict__ Co, float* __restrict__ dtoT) {
  const int blk = blockIdx.x;
  const us8v z8 = { 0, 0, 0, 0, 0, 0, 0, 0 };

  if (blk < NBLK_X) {
    // ---------------- x path ----------------
    const int idx = blk * 256 + threadIdx.x;
    const int tb  = idx / 48, rl = idx % 48;
    const int b   = tb / (SEQLEN / 8);
    const int t0  = (tb % (SEQLEN / 8)) * 8;
    const size_t rowbase = (size_t)b * SEQLEN;
    const int c0 = rl * 8;
    const int h = rl >> 1, i0 = (rl & 1) * 8;

    float w0[8], w1[8], w2[8], w3[8], bias[8];
#pragma unroll
    for (int ch = 0; ch < 8; ++ch) {
      const float4 wv = *(const float4*)(conv_w + (c0 + ch) * 4);
      w0[ch] = wv.x; w1[ch] = wv.y; w2[ch] = wv.z; w3[ch] = wv.w;
      bias[ch] = conv_b[c0 + ch];
    }
    us8v xr[11];
#pragma unroll
    for (int r = 0; r < 11; ++r) {
      const int t = t0 + r - 3;
      xr[r] = (t >= 0) ? *(const us8v*)(zxbdt + (rowbase + t) * D_IN_PROJ + D_INNER + c0) : z8;
    }
#pragma unroll
    for (int tt = 0; tt < 8; ++tt) {
      us8v o;
#pragma unroll
      for (int ch = 0; ch < 8; ++ch) {
        float acc = bias[ch] + w0[ch] * bf2f(xr[tt][ch]) + w1[ch] * bf2f(xr[tt + 1][ch])
                  + w2[ch] * bf2f(xr[tt + 2][ch]) + w3[ch] * bf2f(xr[tt + 3][ch]);
        o[ch] = f2bf(silu_f(acc));
      }
      *(us8v*)(xoT + ((size_t)(b * NHEADS + h) * SEQLEN + t0 + tt) * HEADDIM + i0) = o;
    }
  } else if (blk < NBLK_X + NBLK_BC) {
    // ---------------- B and C paths ----------------
    const int idx = (blk - NBLK_X) * 256 + threadIdx.x;
    const int tb  = idx / 4, q = idx % 4;
    const int b   = tb / (SEQLEN / 8);
    const int t0  = (tb % (SEQLEN / 8)) * 8;
    const size_t rowbase = (size_t)b * SEQLEN;

    if (q < 2) {
      const int c0 = q * 8;
      float w0[8], w1[8], w2[8], w3[8], bias[8];
#pragma unroll
      for (int ch = 0; ch < 8; ++ch) {
        const float4 wv = *(const float4*)(conv_w + (D_INNER + c0 + ch) * 4);
        w0[ch] = wv.x; w1[ch] = wv.y; w2[ch] = wv.z; w3[ch] = wv.w;
        bias[ch] = conv_b[D_INNER + c0 + ch];
      }
      us8v xr[11];
#pragma unroll
      for (int r = 0; r < 11; ++r) {
        const int t = t0 + r - 3;
        xr[r] = (t >= 0) ? *(const us8v*)(zxbdt + (rowbase + t) * D_IN_PROJ + D_INNER + 384 + c0) : z8;
      }
#pragma unroll
      for (int tt = 0; tt < 8; ++tt) {
        us8v o;
#pragma unroll
        for (int ch = 0; ch < 8; ++ch) {
          float acc = bias[ch] + w0[ch] * bf2f(xr[tt][ch]) + w1[ch] * bf2f(xr[tt + 1][ch])
                    + w2[ch] * bf2f(xr[tt + 2][ch]) + w3[ch] * bf2f(xr[tt + 3][ch]);
          o[ch] = f2bf(silu_f(acc));
        }
        *(us8v*)(Bo + (rowbase + t0 + tt) * D_STATE + c0) = o;
      }
    } else {
      const int c0 = (q - 2) * 8;
      float w0[8], w1[8], w2[8], w3[8], bias[8];
#pragma unroll
      for (int ch = 0; ch < 8; ++ch) {
        const float4 wv = *(const float4*)(conv_w_b + (c0 + ch) * 4);
        w0[ch] = wv.x; w1[ch] = wv.y; w2[ch] = wv.z; w3[ch] = wv.w;
        bias[ch] = conv_b_b[c0 + ch];
      }
      us8v xr[11];  // store fp32 cproj rows converted to bf16 (precision loss ok: silu(conv) later vs ref fp32 — conv weights*inputs; acceptable)
#pragma unroll
      for (int r = 0; r < 11; ++r) {
        const int t = t0 + r - 3;
        if (t >= 0) {
          const float4* p = (const float4*)(cproj + (rowbase + t) * D_STATE + c0);
          float4 v0 = p[0], v1 = p[1];
          us8v pk = { f2bf(v0.x), f2bf(v0.y), f2bf(v0.z), f2bf(v0.w),
                      f2bf(v1.x), f2bf(v1.y), f2bf(v1.z), f2bf(v1.w) };
          xr[r] = pk;
        } else xr[r] = z8;
      }
#pragma unroll
      for (int tt = 0; tt < 8; ++tt) {
        us8v o;
#pragma unroll
        for (int ch = 0; ch < 8; ++ch) {
          float acc = bias[ch] + w0[ch] * bf2f(xr[tt][ch]) + w1[ch] * bf2f(xr[tt + 1][ch])
                    + w2[ch] * bf2f(xr[tt + 2][ch]) + w3[ch] * bf2f(xr[tt + 3][ch]);
          o[ch] = f2bf(silu_f(acc));
        }
        *(us8v*)(Co + (rowbase + t0 + tt) * D_STATE + c0) = o;
      }
    }
  } else {
    // ---------------- dt path ----------------
    const int idx = (blk - NBLK_X - NBLK_BC) * 256 + threadIdx.x;
    const int tb  = idx / 24, h = idx % 24;
    const int b   = tb / (SEQLEN / 8);
    const int t0  = (tb % (SEQLEN / 8)) * 8;
    const size_t rowbase = (size_t)b * SEQLEN;
    const float bias = dt_bias[h];
    float o[8];
#pragma unroll
    for (int tt = 0; tt < 8; ++tt) {
      float v = bf2f(zxbdt[(rowbase + t0 + tt) * D_IN_PROJ + (D_IN_PROJ - NHEADS) + h]) + bias;
      o[tt] = softplus_f(v);
    }
    float* dst = dtoT + (size_t)(b * NHEADS + h) * SEQLEN + t0;
    *(float4*)(dst + 0) = make_float4(o[0], o[1], o[2], o[3]);
    *(float4*)(dst + 4) = make_float4(o[4], o[5], o[6], o[7]);
  }
}

// ---------------------------------------------------------------------------
// K3 (MFMA): per (h, chunk, b) block, 4 waves. Head-major in/out.
// ---------------------------------------------------------------------------
__global__ __launch_bounds__(256, 2)
void ssd_mfma_kernel(const unsigned short* __restrict__ xoT, const unsigned short* __restrict__ Bo,
                     const unsigned short* __restrict__ Co, const float* __restrict__ dtoT,
                     const float* __restrict__ A_log,
                     unsigned short* __restrict__ YdT, float* __restrict__ acum_g,
                     float* __restrict__ csum_g, float* __restrict__ stloc) {
  const int h    = blockIdx.x;
  const int cidx = blockIdx.y;
  const int b    = blockIdx.z;
  const int l    = threadIdx.x;
  const int t    = cidx * CHUNK + l;
  const size_t row  = (size_t)b * SEQLEN + t;
  const size_t hrow = (size_t)(b * NHEADS + h) * SEQLEN + t;
  const int wid = l >> 6, lane = l & 63;
  const int fr  = lane & 15, g = lane >> 4;

  __shared__ unsigned short Bs[256 * 24 + 32];
  __shared__ unsigned short Cs[256 * 40];
  __shared__ unsigned short xsT[16 * 264];
  __shared__ unsigned short BwT[16 * 264];
  __shared__ unsigned short Ps[4][16 * 40];
  __shared__ float sc[CHUNK];
  __shared__ float sred[4 * 256];
  __shared__ float wsum[4];

  const float Ah  = -expf(A_log[h]);
  const float dtv = dtoT[hrow];

  float v = dtv * Ah;
#pragma unroll
  for (int off = 1; off < 64; off <<= 1) {
    float u = __shfl_up(v, off, 64);
    if (lane >= off) v += u;
  }
  if (lane == 63) wsum[wid] = v;

  us8v b0, b1;
  {
    const us8v z8 = { 0, 0, 0, 0, 0, 0, 0, 0 };
    const us8v* bp = (const us8v*)(Bo + row * D_STATE);
    b0 = bp[0]; b1 = bp[1];
    *(us8v*)&Bs[l * 24 + 0] = b0;
    *(us8v*)&Bs[l * 24 + 8] = b1;
    *(us8v*)&Bs[l * 24 + 16] = z8;
    if (l < 32) Bs[256 * 24 + l] = 0;
    const us8v* cp = (const us8v*)(Co + row * D_STATE);
    *(us8v*)&Cs[l * 40 + 0]  = cp[0];
    *(us8v*)&Cs[l * 40 + 8]  = cp[1];
    *(us8v*)&Cs[l * 40 + 16] = z8;
    *(us8v*)&Cs[l * 40 + 24] = z8;
    const us8v* xp = (const us8v*)(xoT + hrow * HEADDIM);
    us8v x0 = xp[0], x1 = xp[1];
#pragma unroll
    for (int q = 0; q < 8; ++q) {
      xsT[q * 264 + l]       = f2bf(bf2f(x0[q]) * dtv);
      xsT[(q + 8) * 264 + l] = f2bf(bf2f(x1[q]) * dtv);
    }
  }
  __syncthreads();   // #1

  float pre = 0.f, ctot = 0.f;
#pragma unroll
  for (int w = 0; w < 4; ++w) {
    float s = wsum[w];
    if (w < wid) pre += s;
    ctot += s;
  }
  v += pre;
  sc[l] = v;
  acum_g[hrow] = v;
  if (l == CHUNK - 1) csum_g[(b * NHEADS + h) * NCHUNKS + cidx] = v;
  const float wdv = __expf(ctot - v);
#pragma unroll
  for (int q = 0; q < 8; ++q) {
    BwT[q * 264 + l]       = f2bf(bf2f(b0[q]) * wdv);
    BwT[(q + 8) * 264 + l] = f2bf(bf2f(b1[q]) * wdv);
  }
  __syncthreads();   // #2

  {
    f32x4 accS = {};
    const int s0 = wid * 64;
#pragma unroll
    for (int k2 = 0; k2 < 2; ++k2) {
      bf16x8 af = *(const bf16x8*)&BwT[fr * 264 + s0 + 32 * k2 + 8 * g];
      bf16x8 bb = *(const bf16x8*)&xsT[fr * 264 + s0 + 32 * k2 + 8 * g];
      accS = __builtin_amdgcn_mfma_f32_16x16x32_bf16(af, bb, accS, 0, 0, 0);
    }
    *(f32x4*)&sred[wid * 256 + fr * 16 + 4 * g] = accS;
  }

  const int strips[4] = { wid, 7 - wid, 8 + wid, 15 - wid };
  const f32x4 zf = { 0.f, 0.f, 0.f, 0.f };
#pragma unroll
  for (int q = 0; q < 4; ++q) {
    const int lt = strips[q];
    f32x4 acc = zf;
    const bf16x8 cf = *(const bf16x8*)&Cs[(lt * 16 + fr) * 40 + 8 * g];
    const float acl = sc[lt * 16 + fr];
    const int   lg  = lt * 16 + fr;
    const int npair = (lt + 2) >> 1;
    for (int sp = 0; sp < npair; ++sp) {
#pragma unroll
      for (int ti = 0; ti < 2; ++ti) {
        const int st = 2 * sp + ti;
        if (st <= lt) {
          bf16x8 bfg = *(const bf16x8*)&Bs[(st * 16 + fr) * 24 + 8 * g];
          f32x4 G = __builtin_amdgcn_mfma_f32_16x16x32_bf16(bfg, cf, zf, 0, 0, 0);
          f32x4 se = *(const f32x4*)&sc[st * 16 + 4 * g];
          uint2 pk;
          {
            const int sbase = st * 16 + 4 * g;
            float w0 = (sbase + 0 <= lg) ? __expf(acl - se[0]) : 0.f;
            float w1 = (sbase + 1 <= lg) ? __expf(acl - se[1]) : 0.f;
            float w2 = (sbase + 2 <= lg) ? __expf(acl - se[2]) : 0.f;
            float w3 = (sbase + 3 <= lg) ? __expf(acl - se[3]) : 0.f;
            pk.x = (unsigned)f2bf(G[0] * w0) | ((unsigned)f2bf(G[1] * w1) << 16);
            pk.y = (unsigned)f2bf(G[2] * w2) | ((unsigned)f2bf(G[3] * w3) << 16);
          }
          *(uint2*)&Ps[wid][fr * 40 + 16 * ti + 4 * g] = pk;
        } else {
          uint2 zz; zz.x = 0u; zz.y = 0u;
          *(uint2*)&Ps[wid][fr * 40 + 16 * ti + 4 * g] = zz;
        }
      }
      const bf16x8 pf = *(const bf16x8*)&Ps[wid][fr * 40 + 8 * g];
      const bf16x8 xf = *(const bf16x8*)&xsT[fr * 264 + sp * 32 + 8 * g];
      acc = __builtin_amdgcn_mfma_f32_16x16x32_bf16(xf, pf, acc, 0, 0, 0);
    }
    us4v o = { f2bf(acc[0]), f2bf(acc[1]), f2bf(acc[2]), f2bf(acc[3]) };
    *(us4v*)(YdT + ((size_t)(b * NHEADS + h) * SEQLEN + (size_t)cidx * CHUNK + lt * 16 + fr) * HEADDIM
             + 4 * g) = o;
  }

  __syncthreads();   // #3
  {
    float s = sred[l] + sred[256 + l] + sred[512 + l] + sred[768 + l];
    stloc[((size_t)(b * NCHUNKS + cidx) * NHEADS + h) * 256 + l] = s;
  }
}

// ---------------------------------------------------------------------------
// K4: sequential inter-chunk state recurrence ([p][n] layout)
// ---------------------------------------------------------------------------
__global__ __launch_bounds__(256)
void chunk_scan_kernel(const float* __restrict__ stloc, const float* __restrict__ csum_g,
                       float* __restrict__ stpre) {
  const int b  = blockIdx.x / NHEADS;
  const int h  = blockIdx.x % NHEADS;
  const int pn = threadIdx.x;
  float S = 0.0f;
  for (int c = 0; c < NCHUNKS; ++c) {
    const size_t idx = ((size_t)(b * NCHUNKS + c) * NHEADS + h) * 256 + pn;
    stpre[idx] = S;
    S = __expf(csum_g[(b * NHEADS + h) * NCHUNKS + c]) * S + stloc[idx];
  }
}

// ---------------------------------------------------------------------------
// K5: Y_off + D*x, silu(z) gate, RMSNorm -> row-major bf16 yn
// ---------------------------------------------------------------------------
__global__ __launch_bounds__(384)
void yoff_norm_kernel(const unsigned short* __restrict__ YdT, const unsigned short* __restrict__ xoT,
                      const unsigned short* __restrict__ Co, const float* __restrict__ acum_g,
                      const float* __restrict__ stpre, const float* __restrict__ Dvec,
                      const unsigned short* __restrict__ zxbdt, const float* __restrict__ norm_w,
                      unsigned short* __restrict__ yn) {
  const int row  = blockIdx.x;
  const int b    = row / SEQLEN, t = row % SEQLEN;
  const int cidx = t / CHUNK;
  const int d    = threadIdx.x;
  const int h    = d >> 4, p = d & 15;

  __shared__ float Cl[16];
  __shared__ float red[6];
  if (d < 16) Cl[d] = bf2f(Co[(size_t)row * D_STATE + d]);
  __syncthreads();

  const size_t hrow = (size_t)(b * NHEADS + h) * SEQLEN + t;
  const float* S = stpre + ((size_t)(b * NCHUNKS + cidx) * NHEADS + h) * 256 + p * 16;
  float dot = 0.0f;
#pragma unroll
  for (int n = 0; n < 16; ++n) dot += Cl[n] * S[n];
  const float acl = acum_g[hrow];
  float y = bf2f(YdT[hrow * HEADDIM + p]) + __expf(acl) * dot
          + Dvec[h] * bf2f(xoT[hrow * HEADDIM + p]);
  const float z = bf2f(zxbdt[(size_t)row * D_IN_PROJ + d]);
  const float yg = y * silu_f(z);

  float v = yg * yg;
#pragma unroll
  for (int off = 32; off > 0; off >>= 1) v += __shfl_down(v, off);
  if ((d & 63) == 0) red[d >> 6] = v;
  __syncthreads();
  const float tot = red[0] + red[1] + red[2] + red[3] + red[4] + red[5];
  const float scale = rsqrtf(tot * (1.0f / D_INNER) + EPS);
  yn[(size_t)row * D_INNER + d] = f2bf(yg * scale * norm_w[d]);
}

// ---------------------------------------------------------------------------
extern "C" void kernel_launch(void* const* d_in, const int* in_sizes, int n_in,
                              void* d_out, int out_size, void* d_ws, size_t ws_size,
                              hipStream_t stream) {
  const float* u        = (const float*)d_in[0];
  const float* support  = (const float*)d_in[1];
  const float* W_in     = (const float*)d_in[2];
  const float* W_in_b   = (const float*)d_in[3];
  const float* conv_w   = (const float*)d_in[4];
  const float* conv_b   = (const float*)d_in[5];
  const float* conv_w_b = (const float*)d_in[6];
  const float* conv_b_b = (const float*)d_in[7];
  const float* dt_bias  = (const float*)d_in[8];
  const float* A_log    = (const float*)d_in[9];
  const float* Dvec     = (const float*)d_in[10];
  const float* norm_w   = (const float*)d_in[11];
  const float* W_out    = (const float*)d_in[12];
  float* out = (float*)d_out;
  char* wsb  = (char*)d_ws;

  unsigned short* u_b   = (unsigned short*)(wsb);
  unsigned short* Wi_b  = u_b  + (size_t)ROWS * D_MODEL;
  unsigned short* Wo_b  = Wi_b + (size_t)D_IN_PROJ * D_MODEL;
  unsigned short* zxbdt = Wo_b + (size_t)D_MODEL * D_INNER;
  unsigned short* xoT   = zxbdt + (size_t)ROWS * D_IN_PROJ;      // [b][h][t][16]
  unsigned short* Bo    = xoT + (size_t)ROWS * D_INNER;          // [b][t][16]
  unsigned short* Co    = Bo + (size_t)ROWS * D_STATE;           // [b][t][16]
  unsigned short* YdT   = Co + (size_t)ROWS * D_STATE;           // [b][h][t][16]
  unsigned short* yn    = YdT + (size_t)ROWS * D_INNER;          // [row][384]
  float* cproj = (float*)(yn + (size_t)ROWS * D_INNER);
  float* dtoT  = cproj + (size_t)ROWS * D_STATE;                 // [b][h][t]
  float* acum  = dtoT  + (size_t)ROWS * NHEADS;                  // [b][h][t]
  float* csum  = acum  + (size_t)BATCH * NHEADS * SEQLEN;
  float* stloc = csum  + (size_t)BATCH * NHEADS * NCHUNKS;
  float* stpre = stloc + (size_t)BATCH * NCHUNKS * NHEADS * 256;

  cvt3_kernel<<<2048, 256, 0, stream>>>(u, u_b, (long)ROWS * D_MODEL,
                                        W_in, Wi_b, (long)D_IN_PROJ * D_MODEL,
                                        W_out, Wo_b, (long)D_MODEL * D_INNER);
  gemm_bf16<true><<<dim3((D_IN_PROJ + 127) / 128, ROWS / 128), 256, 0, stream>>>(
      u_b, Wi_b, zxbdt, ROWS, D_IN_PROJ, D_MODEL);
  gemm_nt<64, 16, 16, 4, 1><<<dim3(1, ROWS / 64), 256, 0, stream>>>(
      support, W_in_b, cproj, ROWS, D_STATE, D_MODEL);
  conv_dt_vec<<<NBLK_X + NBLK_BC + NBLK_DT, 256, 0, stream>>>(
      zxbdt, cproj, conv_w, conv_b, conv_w_b, conv_b_b, dt_bias, xoT, Bo, Co, dtoT);
  ssd_mfma_kernel<<<dim3(NHEADS, NCHUNKS, BATCH), 256, 0, stream>>>(
      xoT, Bo, Co, dtoT, A_log, YdT, acum, csum, stloc);
  chunk_scan_kernel<<<BATCH * NHEADS, 256, 0, stream>>>(stloc, csum, stpre);
  yoff_norm_kernel<<<ROWS, 384, 0, stream>>>(YdT, xoT, Co, acum, stpre, Dvec, zxbdt,
                                             norm_w, yn);
  gemm_bf16<false><<<dim3((D_MODEL + 127) / 128, ROWS / 128), 256, 0, stream>>>(
      yn, Wo_b, out, ROWS, D_MODEL, D_INNER);
}

// Round 8
// 178.908 us; speedup vs baseline: 1.1352x; 1.0143x over previous
//
#include <hip/hip_runtime.h>
#include <cmath>

#define ROWS      16384
#define SEQLEN    8192
#define BATCH     2
#define NHEADS    24
#define HEADDIM   16
#define D_STATE   16
#define D_INNER   384
#define D_MODEL   192
#define D_IN_PROJ 808
#define CONV_DIM  400
#define NCHUNKS   32
#define CHUNK     256
#define EPS       1e-5f

typedef short bf16x8 __attribute__((ext_vector_type(8)));
typedef float f32x4  __attribute__((ext_vector_type(4)));
typedef unsigned short us4v __attribute__((ext_vector_type(4)));
typedef unsigned short us8v __attribute__((ext_vector_type(8)));

__device__ __forceinline__ float silu_f(float x) { return x / (1.0f + expf(-x)); }
__device__ __forceinline__ float softplus_f(float x) { return (x > 20.0f) ? x : log1pf(expf(x)); }
__device__ __forceinline__ unsigned short f2bf(float x) {
  unsigned u = __builtin_bit_cast(unsigned, x);
  u += 0x7fff + ((u >> 16) & 1);
  return (unsigned short)(u >> 16);
}
__device__ __forceinline__ float bf2f(unsigned short s) {
  unsigned u = (unsigned)s << 16;
  return __builtin_bit_cast(float, u);
}

// ---------------------------------------------------------------------------
// K0: fp32 -> bf16 conversion for u, W_in, W_out
// ---------------------------------------------------------------------------
__global__ __launch_bounds__(256)
void cvt3_kernel(const float* __restrict__ a, unsigned short* __restrict__ ao, long na,
                 const float* __restrict__ b, unsigned short* __restrict__ bo, long nb,
                 const float* __restrict__ c, unsigned short* __restrict__ co, long nc) {
  const long t0 = na >> 2, t1 = t0 + (nb >> 2), t2 = t1 + (nc >> 2);
  const long stride = (long)gridDim.x * blockDim.x;
  for (long i = (long)blockIdx.x * blockDim.x + threadIdx.x; i < t2; i += stride) {
    const float4* s; us4v* d; long j;
    if (i < t0)      { s = (const float4*)a; d = (us4v*)ao; j = i; }
    else if (i < t1) { s = (const float4*)b; d = (us4v*)bo; j = i - t0; }
    else             { s = (const float4*)c; d = (us4v*)co; j = i - t1; }
    float4 v = s[j];
    us4v o = { f2bf(v.x), f2bf(v.y), f2bf(v.z), f2bf(v.w) };
    d[j] = o;
  }
}

// ---------------------------------------------------------------------------
// MFMA bf16 GEMM: C[M,N] = A[M,K] * W[N,K]^T, double-buffered LDS
// ---------------------------------------------------------------------------
template<bool OUT_BF16>
__launch_bounds__(256, 3)
__global__ void gemm_bf16(const unsigned short* __restrict__ A,
                          const unsigned short* __restrict__ W,
                          void* __restrict__ Cp, int M, int N, int K) {
  constexpr int BM = 128, BN = 128, BK = 32, LDK = 40;
  __shared__ unsigned short As[2][BM * LDK];
  __shared__ unsigned short Ws[2][BN * LDK];
  const int tid  = threadIdx.x;
  const int wid  = tid >> 6, lane = tid & 63;
  const int wr   = wid >> 1, wc = wid & 1;
  const int fr   = lane & 15, fq = lane >> 4;
  const long m0  = (long)blockIdx.y * BM;
  const int  n0  = blockIdx.x * BN;

  f32x4 acc[4][4] = {};

  auto stage = [&](int k0, int buf) {
#pragma unroll
    for (int p = 0; p < 2; ++p) {
      int flat = p * 2048 + tid * 8;
      int r = flat >> 5, c = flat & 31;
      us8v v = *(const us8v*)(A + (m0 + r) * (long)K + k0 + c);
      *(us8v*)&As[buf][r * LDK + c] = v;
    }
#pragma unroll
    for (int p = 0; p < 2; ++p) {
      int flat = p * 2048 + tid * 8;
      int r = flat >> 5, c = flat & 31;
      int gn = n0 + r;
      us8v v = { 0, 0, 0, 0, 0, 0, 0, 0 };
      if (gn < N) v = *(const us8v*)(W + (long)gn * K + k0 + c);
      *(us8v*)&Ws[buf][r * LDK + c] = v;
    }
  };

  const int nk = K / BK;
  stage(0, 0);
  __syncthreads();
  for (int kt = 0; kt < nk; ++kt) {
    const int cur = kt & 1;
    if (kt + 1 < nk) stage((kt + 1) * BK, cur ^ 1);
    bf16x8 af[4], bfr[4];
#pragma unroll
    for (int m = 0; m < 4; ++m)
      af[m] = *(const bf16x8*)&As[cur][(wr * 64 + m * 16 + fr) * LDK + fq * 8];
#pragma unroll
    for (int n = 0; n < 4; ++n)
      bfr[n] = *(const bf16x8*)&Ws[cur][(wc * 64 + n * 16 + fr) * LDK + fq * 8];
#pragma unroll
    for (int m = 0; m < 4; ++m)
#pragma unroll
      for (int n = 0; n < 4; ++n)
        acc[m][n] = __builtin_amdgcn_mfma_f32_16x16x32_bf16(af[m], bfr[n], acc[m][n], 0, 0, 0);
    __syncthreads();
  }

#pragma unroll
  for (int m = 0; m < 4; ++m)
#pragma unroll
    for (int n = 0; n < 4; ++n)
#pragma unroll
      for (int j = 0; j < 4; ++j) {
        long gm = m0 + wr * 64 + m * 16 + fq * 4 + j;
        int  gn = n0 + wc * 64 + n * 16 + fr;
        if (gn < N) {
          if (OUT_BF16) ((unsigned short*)Cp)[gm * N + gn] = f2bf(acc[m][n][j]);
          else          ((float*)Cp)[gm * N + gn] = acc[m][n][j];
        }
      }
}

// ---------------------------------------------------------------------------
// fp32 SIMT GEMM (tiny K1b only: N=16)
// ---------------------------------------------------------------------------
template<int BM, int BN, int BK, int TM, int TN>
__launch_bounds__((BM / TM) * (BN / TN))
__global__ void gemm_nt(const float* __restrict__ A, const float* __restrict__ W,
                        float* __restrict__ C, int M, int N, int K) {
  __shared__ float As[BK][BM + 4];
  __shared__ float Ws[BK][BN + 4];
  constexpr int NTX = BN / TN;
  constexpr int NT  = (BM / TM) * (BN / TN);
  const int tid = threadIdx.x;
  const int tx  = tid % NTX;
  const int ty  = tid / NTX;
  const long m0 = (long)blockIdx.y * BM;
  const long n0 = (long)blockIdx.x * BN;
  float acc[TM][TN] = {};

  for (int k0 = 0; k0 < K; k0 += BK) {
    for (int i = tid; i < BM * BK; i += NT) {
      int m = i / BK, kk = i % BK;
      long gm = m0 + m;
      As[kk][m] = (gm < M) ? A[gm * K + (k0 + kk)] : 0.0f;
    }
    for (int i = tid; i < BN * BK; i += NT) {
      int n = i / BK, kk = i % BK;
      long gn = n0 + n;
      Ws[kk][n] = (gn < N) ? W[gn * K + (k0 + kk)] : 0.0f;
    }
    __syncthreads();
#pragma unroll
    for (int kk = 0; kk < BK; ++kk) {
      float a[TM], w[TN];
#pragma unroll
      for (int i = 0; i < TM; ++i) a[i] = As[kk][ty * TM + i];
#pragma unroll
      for (int j = 0; j < TN; ++j) w[j] = Ws[kk][tx * TN + j];
#pragma unroll
      for (int i = 0; i < TM; ++i)
#pragma unroll
        for (int j = 0; j < TN; ++j)
          acc[i][j] += a[i] * w[j];
    }
    __syncthreads();
  }
#pragma unroll
  for (int i = 0; i < TM; ++i) {
    long gm = m0 + ty * TM + i;
    if (gm >= M) continue;
#pragma unroll
    for (int j = 0; j < TN; ++j) {
      long gn = n0 + tx * TN + j;
      if (gn < N) C[gm * N + gn] = acc[i][j];
    }
  }
}

// ---------------------------------------------------------------------------
// K2: per-row depthwise causal conv + silu + dt softplus (proven r4 shape).
// One block per (b,t) row, 448 threads; bf16 in; head-major xoT/dtoT out.
// Loads are scalar ushort but coalesced (consecutive c -> consecutive addr);
// 16384 blocks give the TLP that hides HBM latency.
// ---------------------------------------------------------------------------
__global__ __launch_bounds__(448)
void conv_dt_row(const unsigned short* __restrict__ zxbdt, const float* __restrict__ cproj,
                 const float* __restrict__ conv_w, const float* __restrict__ conv_b,
                 const float* __restrict__ conv_w_b, const float* __restrict__ conv_b_b,
                 const float* __restrict__ dt_bias,
                 unsigned short* __restrict__ xoT, unsigned short* __restrict__ Bo,
                 unsigned short* __restrict__ Co, float* __restrict__ dtoT) {
  const int row = blockIdx.x;
  const int b   = row / SEQLEN, t = row % SEQLEN;
  const int c   = threadIdx.x;

  if (c < CONV_DIM) {
    const float4 wv = *(const float4*)(conv_w + c * 4);
    const unsigned short* base = zxbdt + (size_t)row * D_IN_PROJ + D_INNER + c;
    const float x0 = (t >= 3) ? bf2f(base[-3 * D_IN_PROJ]) : 0.0f;
    const float x1 = (t >= 2) ? bf2f(base[-2 * D_IN_PROJ]) : 0.0f;
    const float x2 = (t >= 1) ? bf2f(base[-1 * D_IN_PROJ]) : 0.0f;
    const float x3 = bf2f(base[0]);
    float acc = conv_b[c] + wv.x * x0 + wv.y * x1 + wv.z * x2 + wv.w * x3;
    unsigned short y = f2bf(silu_f(acc));
    if (c < D_INNER) {
      const int h = c >> 4, i = c & 15;
      xoT[((size_t)(b * NHEADS + h) * SEQLEN + t) * HEADDIM + i] = y;
    } else {
      Bo[(size_t)row * D_STATE + (c - D_INNER)] = y;
    }
  } else if (c < CONV_DIM + D_STATE) {
    const int cc = c - CONV_DIM;
    const float4 wv = *(const float4*)(conv_w_b + cc * 4);
    const float* base = cproj + (size_t)row * D_STATE + cc;
    const float x0 = (t >= 3) ? base[-3 * D_STATE] : 0.0f;
    const float x1 = (t >= 2) ? base[-2 * D_STATE] : 0.0f;
    const float x2 = (t >= 1) ? base[-1 * D_STATE] : 0.0f;
    const float x3 = base[0];
    float acc = conv_b_b[cc] + wv.x * x0 + wv.y * x1 + wv.z * x2 + wv.w * x3;
    Co[(size_t)row * D_STATE + cc] = f2bf(silu_f(acc));
  } else if (c < CONV_DIM + D_STATE + NHEADS) {
    const int h = c - CONV_DIM - D_STATE;
    float v = bf2f(zxbdt[(size_t)row * D_IN_PROJ + (D_IN_PROJ - NHEADS) + h]) + dt_bias[h];
    dtoT[(size_t)(b * NHEADS + h) * SEQLEN + t] = softplus_f(v);
  }
}

// ---------------------------------------------------------------------------
// K3 (MFMA): per (h, chunk, b) block, 4 waves. Head-major in/out.
// ---------------------------------------------------------------------------
__global__ __launch_bounds__(256, 2)
void ssd_mfma_kernel(const unsigned short* __restrict__ xoT, const unsigned short* __restrict__ Bo,
                     const unsigned short* __restrict__ Co, const float* __restrict__ dtoT,
                     const float* __restrict__ A_log,
                     unsigned short* __restrict__ YdT, float* __restrict__ acum_g,
                     float* __restrict__ csum_g, float* __restrict__ stloc) {
  const int h    = blockIdx.x;
  const int cidx = blockIdx.y;
  const int b    = blockIdx.z;
  const int l    = threadIdx.x;
  const int t    = cidx * CHUNK + l;
  const size_t row  = (size_t)b * SEQLEN + t;
  const size_t hrow = (size_t)(b * NHEADS + h) * SEQLEN + t;
  const int wid = l >> 6, lane = l & 63;
  const int fr  = lane & 15, g = lane >> 4;

  __shared__ unsigned short Bs[256 * 24 + 32];
  __shared__ unsigned short Cs[256 * 40];
  __shared__ unsigned short xsT[16 * 264];
  __shared__ unsigned short BwT[16 * 264];
  __shared__ unsigned short Ps[4][16 * 40];
  __shared__ float sc[CHUNK];
  __shared__ float sred[4 * 256];
  __shared__ float wsum[4];

  const float Ah  = -expf(A_log[h]);
  const float dtv = dtoT[hrow];

  float v = dtv * Ah;
#pragma unroll
  for (int off = 1; off < 64; off <<= 1) {
    float u = __shfl_up(v, off, 64);
    if (lane >= off) v += u;
  }
  if (lane == 63) wsum[wid] = v;

  us8v b0, b1;
  {
    const us8v z8 = { 0, 0, 0, 0, 0, 0, 0, 0 };
    const us8v* bp = (const us8v*)(Bo + row * D_STATE);
    b0 = bp[0]; b1 = bp[1];
    *(us8v*)&Bs[l * 24 + 0] = b0;
    *(us8v*)&Bs[l * 24 + 8] = b1;
    *(us8v*)&Bs[l * 24 + 16] = z8;
    if (l < 32) Bs[256 * 24 + l] = 0;
    const us8v* cp = (const us8v*)(Co + row * D_STATE);
    *(us8v*)&Cs[l * 40 + 0]  = cp[0];
    *(us8v*)&Cs[l * 40 + 8]  = cp[1];
    *(us8v*)&Cs[l * 40 + 16] = z8;
    *(us8v*)&Cs[l * 40 + 24] = z8;
    const us8v* xp = (const us8v*)(xoT + hrow * HEADDIM);
    us8v x0 = xp[0], x1 = xp[1];
#pragma unroll
    for (int q = 0; q < 8; ++q) {
      xsT[q * 264 + l]       = f2bf(bf2f(x0[q]) * dtv);
      xsT[(q + 8) * 264 + l] = f2bf(bf2f(x1[q]) * dtv);
    }
  }
  __syncthreads();   // #1

  float pre = 0.f, ctot = 0.f;
#pragma unroll
  for (int w = 0; w < 4; ++w) {
    float s = wsum[w];
    if (w < wid) pre += s;
    ctot += s;
  }
  v += pre;
  sc[l] = v;
  acum_g[hrow] = v;
  if (l == CHUNK - 1) csum_g[(b * NHEADS + h) * NCHUNKS + cidx] = v;
  const float wdv = __expf(ctot - v);
#pragma unroll
  for (int q = 0; q < 8; ++q) {
    BwT[q * 264 + l]       = f2bf(bf2f(b0[q]) * wdv);
    BwT[(q + 8) * 264 + l] = f2bf(bf2f(b1[q]) * wdv);
  }
  __syncthreads();   // #2

  {
    f32x4 accS = {};
    const int s0 = wid * 64;
#pragma unroll
    for (int k2 = 0; k2 < 2; ++k2) {
      bf16x8 af = *(const bf16x8*)&BwT[fr * 264 + s0 + 32 * k2 + 8 * g];
      bf16x8 bb = *(const bf16x8*)&xsT[fr * 264 + s0 + 32 * k2 + 8 * g];
      accS = __builtin_amdgcn_mfma_f32_16x16x32_bf16(af, bb, accS, 0, 0, 0);
    }
    *(f32x4*)&sred[wid * 256 + fr * 16 + 4 * g] = accS;
  }

  const int strips[4] = { wid, 7 - wid, 8 + wid, 15 - wid };
  const f32x4 zf = { 0.f, 0.f, 0.f, 0.f };
#pragma unroll
  for (int q = 0; q < 4; ++q) {
    const int lt = strips[q];
    f32x4 acc = zf;
    const bf16x8 cf = *(const bf16x8*)&Cs[(lt * 16 + fr) * 40 + 8 * g];
    const float acl = sc[lt * 16 + fr];
    const int   lg  = lt * 16 + fr;
    const int npair = (lt + 2) >> 1;
    for (int sp = 0; sp < npair; ++sp) {
#pragma unroll
      for (int ti = 0; ti < 2; ++ti) {
        const int st = 2 * sp + ti;
        if (st <= lt) {
          bf16x8 bfg = *(const bf16x8*)&Bs[(st * 16 + fr) * 24 + 8 * g];
          f32x4 G = __builtin_amdgcn_mfma_f32_16x16x32_bf16(bfg, cf, zf, 0, 0, 0);
          f32x4 se = *(const f32x4*)&sc[st * 16 + 4 * g];
          uint2 pk;
          {
            const int sbase = st * 16 + 4 * g;
            float w0 = (sbase + 0 <= lg) ? __expf(acl - se[0]) : 0.f;
            float w1 = (sbase + 1 <= lg) ? __expf(acl - se[1]) : 0.f;
            float w2 = (sbase + 2 <= lg) ? __expf(acl - se[2]) : 0.f;
            float w3 = (sbase + 3 <= lg) ? __expf(acl - se[3]) : 0.f;
            pk.x = (unsigned)f2bf(G[0] * w0) | ((unsigned)f2bf(G[1] * w1) << 16);
            pk.y = (unsigned)f2bf(G[2] * w2) | ((unsigned)f2bf(G[3] * w3) << 16);
          }
          *(uint2*)&Ps[wid][fr * 40 + 16 * ti + 4 * g] = pk;
        } else {
          uint2 zz; zz.x = 0u; zz.y = 0u;
          *(uint2*)&Ps[wid][fr * 40 + 16 * ti + 4 * g] = zz;
        }
      }
      const bf16x8 pf = *(const bf16x8*)&Ps[wid][fr * 40 + 8 * g];
      const bf16x8 xf = *(const bf16x8*)&xsT[fr * 264 + sp * 32 + 8 * g];
      acc = __builtin_amdgcn_mfma_f32_16x16x32_bf16(xf, pf, acc, 0, 0, 0);
    }
    us4v o = { f2bf(acc[0]), f2bf(acc[1]), f2bf(acc[2]), f2bf(acc[3]) };
    *(us4v*)(YdT + ((size_t)(b * NHEADS + h) * SEQLEN + (size_t)cidx * CHUNK + lt * 16 + fr) * HEADDIM
             + 4 * g) = o;
  }

  __syncthreads();   // #3
  {
    float s = sred[l] + sred[256 + l] + sred[512 + l] + sred[768 + l];
    stloc[((size_t)(b * NCHUNKS + cidx) * NHEADS + h) * 256 + l] = s;
  }
}

// ---------------------------------------------------------------------------
// K4: sequential inter-chunk state recurrence ([p][n] layout)
// ---------------------------------------------------------------------------
__global__ __launch_bounds__(256)
void chunk_scan_kernel(const float* __restrict__ stloc, const float* __restrict__ csum_g,
                       float* __restrict__ stpre) {
  const int b  = blockIdx.x / NHEADS;
  const int h  = blockIdx.x % NHEADS;
  const int pn = threadIdx.x;
  float S = 0.0f;
  for (int c = 0; c < NCHUNKS; ++c) {
    const size_t idx = ((size_t)(b * NCHUNKS + c) * NHEADS + h) * 256 + pn;
    stpre[idx] = S;
    S = __expf(csum_g[(b * NHEADS + h) * NCHUNKS + c]) * S + stloc[idx];
  }
}

// ---------------------------------------------------------------------------
// K5: Y_off + D*x, silu(z) gate, RMSNorm -> row-major bf16 yn
// ---------------------------------------------------------------------------
__global__ __launch_bounds__(384)
void yoff_norm_kernel(const unsigned short* __restrict__ YdT, const unsigned short* __restrict__ xoT,
                      const unsigned short* __restrict__ Co, const float* __restrict__ acum_g,
                      const float* __restrict__ stpre, const float* __restrict__ Dvec,
                      const unsigned short* __restrict__ zxbdt, const float* __restrict__ norm_w,
                      unsigned short* __restrict__ yn) {
  const int row  = blockIdx.x;
  const int b    = row / SEQLEN, t = row % SEQLEN;
  const int cidx = t / CHUNK;
  const int d    = threadIdx.x;
  const int h    = d >> 4, p = d & 15;

  __shared__ float Cl[16];
  __shared__ float red[6];
  if (d < 16) Cl[d] = bf2f(Co[(size_t)row * D_STATE + d]);
  __syncthreads();

  const size_t hrow = (size_t)(b * NHEADS + h) * SEQLEN + t;
  const float* S = stpre + ((size_t)(b * NCHUNKS + cidx) * NHEADS + h) * 256 + p * 16;
  float dot = 0.0f;
#pragma unroll
  for (int n = 0; n < 16; ++n) dot += Cl[n] * S[n];
  const float acl = acum_g[hrow];
  float y = bf2f(YdT[hrow * HEADDIM + p]) + __expf(acl) * dot
          + Dvec[h] * bf2f(xoT[hrow * HEADDIM + p]);
  const float z = bf2f(zxbdt[(size_t)row * D_IN_PROJ + d]);
  const float yg = y * silu_f(z);

  float v = yg * yg;
#pragma unroll
  for (int off = 32; off > 0; off >>= 1) v += __shfl_down(v, off);
  if ((d & 63) == 0) red[d >> 6] = v;
  __syncthreads();
  const float tot = red[0] + red[1] + red[2] + red[3] + red[4] + red[5];
  const float scale = rsqrtf(tot * (1.0f / D_INNER) + EPS);
  yn[(size_t)row * D_INNER + d] = f2bf(yg * scale * norm_w[d]);
}

// ---------------------------------------------------------------------------
extern "C" void kernel_launch(void* const* d_in, const int* in_sizes, int n_in,
                              void* d_out, int out_size, void* d_ws, size_t ws_size,
                              hipStream_t stream) {
  const float* u        = (const float*)d_in[0];
  const float* support  = (const float*)d_in[1];
  const float* W_in     = (const float*)d_in[2];
  const float* W_in_b   = (const float*)d_in[3];
  const float* conv_w   = (const float*)d_in[4];
  const float* conv_b   = (const float*)d_in[5];
  const float* conv_w_b = (const float*)d_in[6];
  const float* conv_b_b = (const float*)d_in[7];
  const float* dt_bias  = (const float*)d_in[8];
  const float* A_log    = (const float*)d_in[9];
  const float* Dvec     = (const float*)d_in[10];
  const float* norm_w   = (const float*)d_in[11];
  const float* W_out    = (const float*)d_in[12];
  float* out = (float*)d_out;
  char* wsb  = (char*)d_ws;

  unsigned short* u_b   = (unsigned short*)(wsb);
  unsigned short* Wi_b  = u_b  + (size_t)ROWS * D_MODEL;
  unsigned short* Wo_b  = Wi_b + (size_t)D_IN_PROJ * D_MODEL;
  unsigned short* zxbdt = Wo_b + (size_t)D_MODEL * D_INNER;
  unsigned short* xoT   = zxbdt + (size_t)ROWS * D_IN_PROJ;      // [b][h][t][16]
  unsigned short* Bo    = xoT + (size_t)ROWS * D_INNER;          // [b][t][16]
  unsigned short* Co    = Bo + (size_t)ROWS * D_STATE;           // [b][t][16]
  unsigned short* YdT   = Co + (size_t)ROWS * D_STATE;           // [b][h][t][16]
  unsigned short* yn    = YdT + (size_t)ROWS * D_INNER;          // [row][384]
  float* cproj = (float*)(yn + (size_t)ROWS * D_INNER);
  float* dtoT  = cproj + (size_t)ROWS * D_STATE;                 // [b][h][t]
  float* acum  = dtoT  + (size_t)ROWS * NHEADS;                  // [b][h][t]
  float* csum  = acum  + (size_t)BATCH * NHEADS * SEQLEN;
  float* stloc = csum  + (size_t)BATCH * NHEADS * NCHUNKS;
  float* stpre = stloc + (size_t)BATCH * NCHUNKS * NHEADS * 256;

  cvt3_kernel<<<2048, 256, 0, stream>>>(u, u_b, (long)ROWS * D_MODEL,
                                        W_in, Wi_b, (long)D_IN_PROJ * D_MODEL,
                                        W_out, Wo_b, (long)D_MODEL * D_INNER);
  gemm_bf16<true><<<dim3((D_IN_PROJ + 127) / 128, ROWS / 128), 256, 0, stream>>>(
      u_b, Wi_b, zxbdt, ROWS, D_IN_PROJ, D_MODEL);
  gemm_nt<64, 16, 16, 4, 1><<<dim3(1, ROWS / 64), 256, 0, stream>>>(
      support, W_in_b, cproj, ROWS, D_STATE, D_MODEL);
  conv_dt_row<<<ROWS, 448, 0, stream>>>(zxbdt, cproj, conv_w, conv_b, conv_w_b,
                                        conv_b_b, dt_bias, xoT, Bo, Co, dtoT);
  ssd_mfma_kernel<<<dim3(NHEADS, NCHUNKS, BATCH), 256, 0, stream>>>(
      xoT, Bo, Co, dtoT, A_log, YdT, acum, csum, stloc);
  chunk_scan_kernel<<<BATCH * NHEADS, 256, 0, stream>>>(stloc, csum, stpre);
  yoff_norm_kernel<<<ROWS, 384, 0, stream>>>(YdT, xoT, Co, acum, stpre, Dvec, zxbdt,
                                             norm_w, yn);
  gemm_bf16<false><<<dim3((D_MODEL + 127) / 128, ROWS / 128), 256, 0, stream>>>(
      yn, Wo_b, out, ROWS, D_MODEL, D_INNER);
}

// Round 9
// 154.869 us; speedup vs baseline: 1.3114x; 1.1552x over previous
//
#include <hip/hip_runtime.h>
#include <cmath>

#define ROWS      16384
#define SEQLEN    8192
#define BATCH     2
#define NHEADS    24
#define HEADDIM   16
#define D_STATE   16
#define D_INNER   384
#define D_MODEL   192
#define D_IN_PROJ 808
#define CONV_DIM  400
#define NCHUNKS   32
#define CHUNK     256
#define EPS       1e-5f

typedef short bf16x8 __attribute__((ext_vector_type(8)));
typedef float f32x4  __attribute__((ext_vector_type(4)));
typedef unsigned short us4v __attribute__((ext_vector_type(4)));
typedef unsigned short us8v __attribute__((ext_vector_type(8)));

__device__ __forceinline__ float silu_f(float x) { return x / (1.0f + expf(-x)); }
__device__ __forceinline__ float softplus_f(float x) { return (x > 20.0f) ? x : log1pf(expf(x)); }
__device__ __forceinline__ unsigned short f2bf(float x) {
  unsigned u = __builtin_bit_cast(unsigned, x);
  u += 0x7fff + ((u >> 16) & 1);
  return (unsigned short)(u >> 16);
}
__device__ __forceinline__ float bf2f(unsigned short s) {
  unsigned u = (unsigned)s << 16;
  return __builtin_bit_cast(float, u);
}

// ---------------------------------------------------------------------------
// K0: fp32 -> bf16 conversion for u, W_in, W_out
// ---------------------------------------------------------------------------
__global__ __launch_bounds__(256)
void cvt3_kernel(const float* __restrict__ a, unsigned short* __restrict__ ao, long na,
                 const float* __restrict__ b, unsigned short* __restrict__ bo, long nb,
                 const float* __restrict__ c, unsigned short* __restrict__ co, long nc) {
  const long t0 = na >> 2, t1 = t0 + (nb >> 2), t2 = t1 + (nc >> 2);
  const long stride = (long)gridDim.x * blockDim.x;
  for (long i = (long)blockIdx.x * blockDim.x + threadIdx.x; i < t2; i += stride) {
    const float4* s; us4v* d; long j;
    if (i < t0)      { s = (const float4*)a; d = (us4v*)ao; j = i; }
    else if (i < t1) { s = (const float4*)b; d = (us4v*)bo; j = i - t0; }
    else             { s = (const float4*)c; d = (us4v*)co; j = i - t1; }
    float4 v = s[j];
    us4v o = { f2bf(v.x), f2bf(v.y), f2bf(v.z), f2bf(v.w) };
    d[j] = o;
  }
}

// ---------------------------------------------------------------------------
// MFMA bf16 GEMM: C[M,N] = A[M,K] * W[N,K]^T, double-buffered LDS
// ---------------------------------------------------------------------------
template<bool OUT_BF16>
__launch_bounds__(256, 3)
__global__ void gemm_bf16(const unsigned short* __restrict__ A,
                          const unsigned short* __restrict__ W,
                          void* __restrict__ Cp, int M, int N, int K) {
  constexpr int BM = 128, BN = 128, BK = 32, LDK = 40;
  __shared__ unsigned short As[2][BM * LDK];
  __shared__ unsigned short Ws[2][BN * LDK];
  const int tid  = threadIdx.x;
  const int wid  = tid >> 6, lane = tid & 63;
  const int wr   = wid >> 1, wc = wid & 1;
  const int fr   = lane & 15, fq = lane >> 4;
  const long m0  = (long)blockIdx.y * BM;
  const int  n0  = blockIdx.x * BN;

  f32x4 acc[4][4] = {};

  auto stage = [&](int k0, int buf) {
#pragma unroll
    for (int p = 0; p < 2; ++p) {
      int flat = p * 2048 + tid * 8;
      int r = flat >> 5, c = flat & 31;
      us8v v = *(const us8v*)(A + (m0 + r) * (long)K + k0 + c);
      *(us8v*)&As[buf][r * LDK + c] = v;
    }
#pragma unroll
    for (int p = 0; p < 2; ++p) {
      int flat = p * 2048 + tid * 8;
      int r = flat >> 5, c = flat & 31;
      int gn = n0 + r;
      us8v v = { 0, 0, 0, 0, 0, 0, 0, 0 };
      if (gn < N) v = *(const us8v*)(W + (long)gn * K + k0 + c);
      *(us8v*)&Ws[buf][r * LDK + c] = v;
    }
  };

  const int nk = K / BK;
  stage(0, 0);
  __syncthreads();
  for (int kt = 0; kt < nk; ++kt) {
    const int cur = kt & 1;
    if (kt + 1 < nk) stage((kt + 1) * BK, cur ^ 1);
    bf16x8 af[4], bfr[4];
#pragma unroll
    for (int m = 0; m < 4; ++m)
      af[m] = *(const bf16x8*)&As[cur][(wr * 64 + m * 16 + fr) * LDK + fq * 8];
#pragma unroll
    for (int n = 0; n < 4; ++n)
      bfr[n] = *(const bf16x8*)&Ws[cur][(wc * 64 + n * 16 + fr) * LDK + fq * 8];
#pragma unroll
    for (int m = 0; m < 4; ++m)
#pragma unroll
      for (int n = 0; n < 4; ++n)
        acc[m][n] = __builtin_amdgcn_mfma_f32_16x16x32_bf16(af[m], bfr[n], acc[m][n], 0, 0, 0);
    __syncthreads();
  }

#pragma unroll
  for (int m = 0; m < 4; ++m)
#pragma unroll
    for (int n = 0; n < 4; ++n)
#pragma unroll
      for (int j = 0; j < 4; ++j) {
        long gm = m0 + wr * 64 + m * 16 + fq * 4 + j;
        int  gn = n0 + wc * 64 + n * 16 + fr;
        if (gn < N) {
          if (OUT_BF16) ((unsigned short*)Cp)[gm * N + gn] = f2bf(acc[m][n][j]);
          else          ((float*)Cp)[gm * N + gn] = acc[m][n][j];
        }
      }
}

// ---------------------------------------------------------------------------
// fp32 SIMT GEMM (tiny K1b only: N=16)
// ---------------------------------------------------------------------------
template<int BM, int BN, int BK, int TM, int TN>
__launch_bounds__((BM / TM) * (BN / TN))
__global__ void gemm_nt(const float* __restrict__ A, const float* __restrict__ W,
                        float* __restrict__ C, int M, int N, int K) {
  __shared__ float As[BK][BM + 4];
  __shared__ float Ws[BK][BN + 4];
  constexpr int NTX = BN / TN;
  constexpr int NT  = (BM / TM) * (BN / TN);
  const int tid = threadIdx.x;
  const int tx  = tid % NTX;
  const int ty  = tid / NTX;
  const long m0 = (long)blockIdx.y * BM;
  const long n0 = (long)blockIdx.x * BN;
  float acc[TM][TN] = {};

  for (int k0 = 0; k0 < K; k0 += BK) {
    for (int i = tid; i < BM * BK; i += NT) {
      int m = i / BK, kk = i % BK;
      long gm = m0 + m;
      As[kk][m] = (gm < M) ? A[gm * K + (k0 + kk)] : 0.0f;
    }
    for (int i = tid; i < BN * BK; i += NT) {
      int n = i / BK, kk = i % BK;
      long gn = n0 + n;
      Ws[kk][n] = (gn < N) ? W[gn * K + (k0 + kk)] : 0.0f;
    }
    __syncthreads();
#pragma unroll
    for (int kk = 0; kk < BK; ++kk) {
      float a[TM], w[TN];
#pragma unroll
      for (int i = 0; i < TM; ++i) a[i] = As[kk][ty * TM + i];
#pragma unroll
      for (int j = 0; j < TN; ++j) w[j] = Ws[kk][tx * TN + j];
#pragma unroll
      for (int i = 0; i < TM; ++i)
#pragma unroll
        for (int j = 0; j < TN; ++j)
          acc[i][j] += a[i] * w[j];
    }
    __syncthreads();
  }
#pragma unroll
  for (int i = 0; i < TM; ++i) {
    long gm = m0 + ty * TM + i;
    if (gm >= M) continue;
#pragma unroll
    for (int j = 0; j < TN; ++j) {
      long gn = n0 + tx * TN + j;
      if (gn < N) C[gm * N + gn] = acc[i][j];
    }
  }
}

// ---------------------------------------------------------------------------
// K2: per-row depthwise causal conv + silu + dt softplus.
// ---------------------------------------------------------------------------
__global__ __launch_bounds__(448)
void conv_dt_row(const unsigned short* __restrict__ zxbdt, const float* __restrict__ cproj,
                 const float* __restrict__ conv_w, const float* __restrict__ conv_b,
                 const float* __restrict__ conv_w_b, const float* __restrict__ conv_b_b,
                 const float* __restrict__ dt_bias,
                 unsigned short* __restrict__ xoT, unsigned short* __restrict__ Bo,
                 unsigned short* __restrict__ Co, float* __restrict__ dtoT) {
  const int row = blockIdx.x;
  const int b   = row / SEQLEN, t = row % SEQLEN;
  const int c   = threadIdx.x;

  if (c < CONV_DIM) {
    const float4 wv = *(const float4*)(conv_w + c * 4);
    const unsigned short* base = zxbdt + (size_t)row * D_IN_PROJ + D_INNER + c;
    const float x0 = (t >= 3) ? bf2f(base[-3 * D_IN_PROJ]) : 0.0f;
    const float x1 = (t >= 2) ? bf2f(base[-2 * D_IN_PROJ]) : 0.0f;
    const float x2 = (t >= 1) ? bf2f(base[-1 * D_IN_PROJ]) : 0.0f;
    const float x3 = bf2f(base[0]);
    float acc = conv_b[c] + wv.x * x0 + wv.y * x1 + wv.z * x2 + wv.w * x3;
    unsigned short y = f2bf(silu_f(acc));
    if (c < D_INNER) {
      const int h = c >> 4, i = c & 15;
      xoT[((size_t)(b * NHEADS + h) * SEQLEN + t) * HEADDIM + i] = y;
    } else {
      Bo[(size_t)row * D_STATE + (c - D_INNER)] = y;
    }
  } else if (c < CONV_DIM + D_STATE) {
    const int cc = c - CONV_DIM;
    const float4 wv = *(const float4*)(conv_w_b + cc * 4);
    const float* base = cproj + (size_t)row * D_STATE + cc;
    const float x0 = (t >= 3) ? base[-3 * D_STATE] : 0.0f;
    const float x1 = (t >= 2) ? base[-2 * D_STATE] : 0.0f;
    const float x2 = (t >= 1) ? base[-1 * D_STATE] : 0.0f;
    const float x3 = base[0];
    float acc = conv_b_b[cc] + wv.x * x0 + wv.y * x1 + wv.z * x2 + wv.w * x3;
    Co[(size_t)row * D_STATE + cc] = f2bf(silu_f(acc));
  } else if (c < CONV_DIM + D_STATE + NHEADS) {
    const int h = c - CONV_DIM - D_STATE;
    float v = bf2f(zxbdt[(size_t)row * D_IN_PROJ + (D_IN_PROJ - NHEADS) + h]) + dt_bias[h];
    dtoT[(size_t)(b * NHEADS + h) * SEQLEN + t] = softplus_f(v);
  }
}

// ---------------------------------------------------------------------------
// K3 (MFMA): per (h, chunk, b) block, 4 waves. Head-major in/out.
// LDS diet: no Cs (C fragments straight from L2-resident Co; g>=2 lanes hold
// the K-pad zeros in registers), no sred (wave 0 owns the full state MFMA).
// 35 KB LDS -> 4 blocks/CU.
// ---------------------------------------------------------------------------
__global__ __launch_bounds__(256, 4)
void ssd_mfma_kernel(const unsigned short* __restrict__ xoT, const unsigned short* __restrict__ Bo,
                     const unsigned short* __restrict__ Co, const float* __restrict__ dtoT,
                     const float* __restrict__ A_log,
                     unsigned short* __restrict__ YdT, float* __restrict__ acum_g,
                     float* __restrict__ csum_g, float* __restrict__ stloc) {
  const int h    = blockIdx.x;
  const int cidx = blockIdx.y;
  const int b    = blockIdx.z;
  const int l    = threadIdx.x;
  const int t    = cidx * CHUNK + l;
  const size_t row  = (size_t)b * SEQLEN + t;
  const size_t hrow = (size_t)(b * NHEADS + h) * SEQLEN + t;
  const int wid = l >> 6, lane = l & 63;
  const int fr  = lane & 15, g = lane >> 4;

  __shared__ unsigned short Bs[256 * 24 + 32];
  __shared__ unsigned short xsT[16 * 264];
  __shared__ unsigned short BwT[16 * 264];
  __shared__ unsigned short Ps[4][16 * 40];
  __shared__ float sc[CHUNK];
  __shared__ float wsum[4];

  const float Ah  = -expf(A_log[h]);
  const float dtv = dtoT[hrow];

  float v = dtv * Ah;
#pragma unroll
  for (int off = 1; off < 64; off <<= 1) {
    float u = __shfl_up(v, off, 64);
    if (lane >= off) v += u;
  }
  if (lane == 63) wsum[wid] = v;

  us8v b0, b1;
  {
    const us8v z8 = { 0, 0, 0, 0, 0, 0, 0, 0 };
    const us8v* bp = (const us8v*)(Bo + row * D_STATE);
    b0 = bp[0]; b1 = bp[1];
    *(us8v*)&Bs[l * 24 + 0] = b0;
    *(us8v*)&Bs[l * 24 + 8] = b1;
    *(us8v*)&Bs[l * 24 + 16] = z8;
    if (l < 32) Bs[256 * 24 + l] = 0;
    const us8v* xp = (const us8v*)(xoT + hrow * HEADDIM);
    us8v x0 = xp[0], x1 = xp[1];
#pragma unroll
    for (int q = 0; q < 8; ++q) {
      xsT[q * 264 + l]       = f2bf(bf2f(x0[q]) * dtv);
      xsT[(q + 8) * 264 + l] = f2bf(bf2f(x1[q]) * dtv);
    }
  }
  __syncthreads();   // #1

  float pre = 0.f, ctot = 0.f;
#pragma unroll
  for (int w = 0; w < 4; ++w) {
    float s = wsum[w];
    if (w < wid) pre += s;
    ctot += s;
  }
  v += pre;
  sc[l] = v;
  acum_g[hrow] = v;
  if (l == CHUNK - 1) csum_g[(b * NHEADS + h) * NCHUNKS + cidx] = v;
  const float wdv = __expf(ctot - v);
#pragma unroll
  for (int q = 0; q < 8; ++q) {
    BwT[q * 264 + l]       = f2bf(bf2f(b0[q]) * wdv);
    BwT[(q + 8) * 264 + l] = f2bf(bf2f(b1[q]) * wdv);
  }
  __syncthreads();   // #2

  // chunk state: wave 0 computes all of K=256 (8 MFMAs), writes stloc direct
  if (wid == 0) {
    f32x4 accS = {};
#pragma unroll
    for (int k2 = 0; k2 < 8; ++k2) {
      bf16x8 af = *(const bf16x8*)&BwT[fr * 264 + 32 * k2 + 8 * g];
      bf16x8 bb = *(const bf16x8*)&xsT[fr * 264 + 32 * k2 + 8 * g];
      accS = __builtin_amdgcn_mfma_f32_16x16x32_bf16(af, bb, accS, 0, 0, 0);
    }
    // lane holds state[n=4g+jr][p=fr] -> store [p][n] layout
    *(f32x4*)&stloc[((size_t)(b * NCHUNKS + cidx) * NHEADS + h) * 256 + fr * 16 + 4 * g] = accS;
  }

  // Y_diag strips
  const int strips[4] = { wid, 7 - wid, 8 + wid, 15 - wid };
  const f32x4 zf = { 0.f, 0.f, 0.f, 0.f };
  const unsigned short* Cbase = Co + ((size_t)b * SEQLEN + (size_t)cidx * CHUNK) * D_STATE;
#pragma unroll
  for (int q = 0; q < 4; ++q) {
    const int lt = strips[q];
    f32x4 acc = zf;
    bf16x8 cf = { 0, 0, 0, 0, 0, 0, 0, 0 };
    if (g < 2) cf = *(const bf16x8*)(Cbase + (lt * 16 + fr) * D_STATE + 8 * g);
    const float acl = sc[lt * 16 + fr];
    const int   lg  = lt * 16 + fr;
    const int npair = (lt + 2) >> 1;
    for (int sp = 0; sp < npair; ++sp) {
#pragma unroll
      for (int ti = 0; ti < 2; ++ti) {
        const int st = 2 * sp + ti;
        if (st <= lt) {
          bf16x8 bfg = *(const bf16x8*)&Bs[(st * 16 + fr) * 24 + 8 * g];
          f32x4 G = __builtin_amdgcn_mfma_f32_16x16x32_bf16(bfg, cf, zf, 0, 0, 0);
          f32x4 se = *(const f32x4*)&sc[st * 16 + 4 * g];
          uint2 pk;
          {
            const int sbase = st * 16 + 4 * g;
            float w0 = (sbase + 0 <= lg) ? __expf(acl - se[0]) : 0.f;
            float w1 = (sbase + 1 <= lg) ? __expf(acl - se[1]) : 0.f;
            float w2 = (sbase + 2 <= lg) ? __expf(acl - se[2]) : 0.f;
            float w3 = (sbase + 3 <= lg) ? __expf(acl - se[3]) : 0.f;
            pk.x = (unsigned)f2bf(G[0] * w0) | ((unsigned)f2bf(G[1] * w1) << 16);
            pk.y = (unsigned)f2bf(G[2] * w2) | ((unsigned)f2bf(G[3] * w3) << 16);
          }
          *(uint2*)&Ps[wid][fr * 40 + 16 * ti + 4 * g] = pk;
        } else {
          uint2 zz; zz.x = 0u; zz.y = 0u;
          *(uint2*)&Ps[wid][fr * 40 + 16 * ti + 4 * g] = zz;
        }
      }
      const bf16x8 pf = *(const bf16x8*)&Ps[wid][fr * 40 + 8 * g];
      const bf16x8 xf = *(const bf16x8*)&xsT[fr * 264 + sp * 32 + 8 * g];
      acc = __builtin_amdgcn_mfma_f32_16x16x32_bf16(xf, pf, acc, 0, 0, 0);
    }
    us4v o = { f2bf(acc[0]), f2bf(acc[1]), f2bf(acc[2]), f2bf(acc[3]) };
    *(us4v*)(YdT + ((size_t)(b * NHEADS + h) * SEQLEN + (size_t)cidx * CHUNK + lt * 16 + fr) * HEADDIM
             + 4 * g) = o;
  }
}

// ---------------------------------------------------------------------------
// K4: sequential inter-chunk state recurrence ([p][n] layout)
// ---------------------------------------------------------------------------
__global__ __launch_bounds__(256)
void chunk_scan_kernel(const float* __restrict__ stloc, const float* __restrict__ csum_g,
                       float* __restrict__ stpre) {
  const int b  = blockIdx.x / NHEADS;
  const int h  = blockIdx.x % NHEADS;
  const int pn = threadIdx.x;
  float S = 0.0f;
  for (int c = 0; c < NCHUNKS; ++c) {
    const size_t idx = ((size_t)(b * NCHUNKS + c) * NHEADS + h) * 256 + pn;
    stpre[idx] = S;
    S = __expf(csum_g[(b * NHEADS + h) * NCHUNKS + c]) * S + stloc[idx];
  }
}

// ---------------------------------------------------------------------------
// K5 (tiled): Y_off + D*x, silu(z) gate, RMSNorm -> row-major bf16 yn.
// Block = 16 rows x 384 channels. Head-major Yd/x/acum staged contiguously
// into LDS; per-thread state slice S[h][p][0..15] kept in 16 registers.
// ---------------------------------------------------------------------------
#define TT 16
__global__ __launch_bounds__(384)
void yoff_norm_tiled(const unsigned short* __restrict__ YdT, const unsigned short* __restrict__ xoT,
                     const unsigned short* __restrict__ Co, const float* __restrict__ acum_g,
                     const float* __restrict__ stpre, const float* __restrict__ Dvec,
                     const unsigned short* __restrict__ zxbdt, const float* __restrict__ norm_w,
                     unsigned short* __restrict__ yn) {
  const int r0   = blockIdx.x * TT;            // global row of first tile row
  const int b    = r0 / SEQLEN;
  const int t0   = r0 % SEQLEN;
  const int cidx = t0 / CHUNK;
  const int d    = threadIdx.x;                // channel 0..383
  const int h    = d >> 4, p = d & 15;
  const int wv   = d >> 6;                     // wave id (0..5)

  __shared__ unsigned short Yt[NHEADS * TT * 16];  // [h][tt][p]
  __shared__ unsigned short Xt[NHEADS * TT * 16];
  __shared__ float At[NHEADS * TT];                // [h][tt]
  __shared__ float Ct[TT * 16];                    // [tt][n] fp32
  __shared__ float red[TT][6];

  // ---- staging ----
  {
    us8v* Yt8 = (us8v*)Yt;
    us8v* Xt8 = (us8v*)Xt;
#pragma unroll
    for (int rep = 0; rep < 2; ++rep) {
      int j = d + rep * 384;                     // 0..767
      int hh = j >> 5, q = j & 31;
      const size_t src = ((size_t)(b * NHEADS + hh) * SEQLEN + t0) * HEADDIM + q * 8;
      Yt8[j] = *(const us8v*)(YdT + src);
      Xt8[j] = *(const us8v*)(xoT + src);
    }
    At[d] = acum_g[(size_t)(b * NHEADS + (d >> 4)) * SEQLEN + t0 + (d & 15)];
    if (d < TT * 16) Ct[d] = bf2f(Co[(size_t)r0 * D_STATE + d]);
  }

  // per-thread state slice (global, L2-resident: 24KB/chunk-slice)
  float S[16];
  {
    const float* Sp = stpre + ((size_t)(b * NCHUNKS + cidx) * NHEADS + h) * 256 + p * 16;
#pragma unroll
    for (int q = 0; q < 4; ++q) {
      float4 v4 = *(const float4*)(Sp + 4 * q);
      S[4 * q + 0] = v4.x; S[4 * q + 1] = v4.y; S[4 * q + 2] = v4.z; S[4 * q + 3] = v4.w;
    }
  }
  const float Dh = Dvec[h];
  const float nw = norm_w[d];
  __syncthreads();

  // ---- compute yg for all 16 rows; per-row wave-partial sumsq ----
  float yg[TT];
#pragma unroll
  for (int tt = 0; tt < TT; ++tt) {
    float dot = 0.f;
#pragma unroll
    for (int n = 0; n < 16; ++n) dot += Ct[tt * 16 + n] * S[n];
    const float acl = At[h * TT + tt];
    float y = bf2f(Yt[h * 256 + tt * 16 + p]) + __expf(acl) * dot
            + Dh * bf2f(Xt[h * 256 + tt * 16 + p]);
    const float z = bf2f(zxbdt[(size_t)(r0 + tt) * D_IN_PROJ + d]);
    yg[tt] = y * silu_f(z);
    float s = yg[tt] * yg[tt];
#pragma unroll
    for (int off = 32; off > 0; off >>= 1) s += __shfl_down(s, off);
    if ((d & 63) == 0) red[tt][wv] = s;
  }
  __syncthreads();

#pragma unroll
  for (int tt = 0; tt < TT; ++tt) {
    const float tot = red[tt][0] + red[tt][1] + red[tt][2] + red[tt][3] + red[tt][4] + red[tt][5];
    const float scale = rsqrtf(tot * (1.0f / D_INNER) + EPS);
    yn[(size_t)(r0 + tt) * D_INNER + d] = f2bf(yg[tt] * scale * nw);
  }
}

// ---------------------------------------------------------------------------
extern "C" void kernel_launch(void* const* d_in, const int* in_sizes, int n_in,
                              void* d_out, int out_size, void* d_ws, size_t ws_size,
                              hipStream_t stream) {
  const float* u        = (const float*)d_in[0];
  const float* support  = (const float*)d_in[1];
  const float* W_in     = (const float*)d_in[2];
  const float* W_in_b   = (const float*)d_in[3];
  const float* conv_w   = (const float*)d_in[4];
  const float* conv_b   = (const float*)d_in[5];
  const float* conv_w_b = (const float*)d_in[6];
  const float* conv_b_b = (const float*)d_in[7];
  const float* dt_bias  = (const float*)d_in[8];
  const float* A_log    = (const float*)d_in[9];
  const float* Dvec     = (const float*)d_in[10];
  const float* norm_w   = (const float*)d_in[11];
  const float* W_out    = (const float*)d_in[12];
  float* out = (float*)d_out;
  char* wsb  = (char*)d_ws;

  unsigned short* u_b   = (unsigned short*)(wsb);
  unsigned short* Wi_b  = u_b  + (size_t)ROWS * D_MODEL;
  unsigned short* Wo_b  = Wi_b + (size_t)D_IN_PROJ * D_MODEL;
  unsigned short* zxbdt = Wo_b + (size_t)D_MODEL * D_INNER;
  unsigned short* xoT   = zxbdt + (size_t)ROWS * D_IN_PROJ;      // [b][h][t][16]
  unsigned short* Bo    = xoT + (size_t)ROWS * D_INNER;          // [b][t][16]
  unsigned short* Co    = Bo + (size_t)ROWS * D_STATE;           // [b][t][16]
  unsigned short* YdT   = Co + (size_t)ROWS * D_STATE;           // [b][h][t][16]
  unsigned short* yn    = YdT + (size_t)ROWS * D_INNER;          // [row][384]
  float* cproj = (float*)(yn + (size_t)ROWS * D_INNER);
  float* dtoT  = cproj + (size_t)ROWS * D_STATE;                 // [b][h][t]
  float* acum  = dtoT  + (size_t)ROWS * NHEADS;                  // [b][h][t]
  float* csum  = acum  + (size_t)BATCH * NHEADS * SEQLEN;
  float* stloc = csum  + (size_t)BATCH * NHEADS * NCHUNKS;
  float* stpre = stloc + (size_t)BATCH * NCHUNKS * NHEADS * 256;

  cvt3_kernel<<<2048, 256, 0, stream>>>(u, u_b, (long)ROWS * D_MODEL,
                                        W_in, Wi_b, (long)D_IN_PROJ * D_MODEL,
                                        W_out, Wo_b, (long)D_MODEL * D_INNER);
  gemm_bf16<true><<<dim3((D_IN_PROJ + 127) / 128, ROWS / 128), 256, 0, stream>>>(
      u_b, Wi_b, zxbdt, ROWS, D_IN_PROJ, D_MODEL);
  gemm_nt<64, 16, 16, 4, 1><<<dim3(1, ROWS / 64), 256, 0, stream>>>(
      support, W_in_b, cproj, ROWS, D_STATE, D_MODEL);
  conv_dt_row<<<ROWS, 448, 0, stream>>>(zxbdt, cproj, conv_w, conv_b, conv_w_b,
                                        conv_b_b, dt_bias, xoT, Bo, Co, dtoT);
  ssd_mfma_kernel<<<dim3(NHEADS, NCHUNKS, BATCH), 256, 0, stream>>>(
      xoT, Bo, Co, dtoT, A_log, YdT, acum, csum, stloc);
  chunk_scan_kernel<<<BATCH * NHEADS, 256, 0, stream>>>(stloc, csum, stpre);
  yoff_norm_tiled<<<ROWS / TT, 384, 0, stream>>>(YdT, xoT, Co, acum, stpre, Dvec, zxbdt,
                                                 norm_w, yn);
  gemm_bf16<false><<<dim3((D_MODEL + 127) / 128, ROWS / 128), 256, 0, stream>>>(
      yn, Wo_b, out, ROWS, D_MODEL, D_INNER);
}